// Round 6
// baseline (3917.260 us; speedup 1.0000x reference)
//
#include <hip/hip_runtime.h>
#include <math.h>

#define EPSF 1e-6f

#define NL 4
#define NB 8
#define NE 1024
#define NH 16
#define NG 4096
#define NIMG 256
#define NTT 64
#define NV 16385
#define NVPAD 17408
#define NBLK 256
#define NSLICE 21

// ---- ws float offsets ----
#define P_QKV   0          // [3][32][8][1024]
#define P_FC01  786432     // [2][16][8][4096]
#define P_FC2   1835008    // [64][8][1024]
#define P_LM    2359296    // [8][8][17408]
#define SSPART  3473408    // [16][8][1024]
#define SEPART  3604480    // [16][8][1024]
#define XBUF    3735552    // [8][1024]
#define DH1     3743744
#define DX2     3751936
#define DX3     3760128
#define DH3     3768320
#define DHG     3776512    // [8][4096]
#define DHF     3809280
#define BARRF   3817472    // 64 uints (barrier slots + mask flag @48)

struct MegaP {
  const float *enc, *ast_in;
  const void* mask;
  const int *prev, *tix;
  const float *etok, *epos, *lnemb_s, *lnemb_b;
  const float *psb, *Wsq, *Wsk, *Wsv, *Wso, *sls, *slb, *peb;
  const float *Weq, *Wek, *Wev, *Weo, *els, *elb;
  const float *g0b, *Wf0, *Wf1, *g1b, *Wf2, *flb, *Wlm;
  float *logits, *out_ast, *ws;
};

__device__ inline void wave_red2(float& a, float& b) {
#pragma unroll
  for (int o = 32; o; o >>= 1) { a += __shfl_xor(a, o); b += __shfl_xor(b, o); }
}

__device__ inline void block_red2(float& s, float& ss, float* tmp) {
  wave_red2(s, ss);
  int wv = threadIdx.x >> 6, ln = threadIdx.x & 63;
  if (ln == 0) { tmp[wv] = s; tmp[4 + wv] = ss; }
  __syncthreads();
  s = tmp[0] + tmp[1] + tmp[2] + tmp[3];
  ss = tmp[4] + tmp[5] + tmp[6] + tmp[7];
  __syncthreads();
}

__device__ inline float4 f4add(float4 a, float4 b) {
  return make_float4(a.x + b.x, a.y + b.y, a.z + b.z, a.w + b.w);
}

// device-scope grid barrier; one monotonic slot per phase (memset to 0 each call)
__device__ inline void gbar(unsigned* slot) {
  __syncthreads();
  if (threadIdx.x == 0) {
    __threadfence();
    __hip_atomic_fetch_add(slot, 1u, __ATOMIC_ACQ_REL, __HIP_MEMORY_SCOPE_AGENT);
    while (__hip_atomic_load(slot, __ATOMIC_ACQUIRE, __HIP_MEMORY_SCOPE_AGENT) < (unsigned)NBLK) {
      __builtin_amdgcn_s_sleep(2);
    }
    __threadfence();
  }
  __syncthreads();
}

// copy a slice of attention_state passthrough, skipping row==tixc (written fresh)
__device__ inline void copy_slice(const float4* __restrict__ src, float4* __restrict__ dst,
                                  int idx, int bid0, int nidle, int tixc) {
  const int n4 = NL * 16 * NIMG * (NE / 4);
  const int CH = (n4 + NSLICE - 1) / NSLICE;
  int s = idx * CH, e = s + CH; if (e > n4) e = n4;
  for (int i = s + (blockIdx.x - bid0) * 256 + (int)threadIdx.x; i < e; i += nidle * 256) {
    int row = (i >> 8) & 255;
    if (row != tixc) dst[i] = src[i];
  }
}

// one matvec work unit: pout[8][NPAD] (cols n0..n0+1023) = h(8xBK from hsrc@k0) @ W
__device__ void mv_unit(const float* __restrict__ W, const float* __restrict__ hsrc,
                        float* __restrict__ pout, int K, int N, int NPAD,
                        int BK, int k0, int n0, float* h) {
  const int tid = threadIdx.x;
  const int bk4 = BK >> 2;
  for (int i = tid; i < 8 * bk4; i += 256) {
    int r = i / bk4, q = i - r * bk4;
    reinterpret_cast<float4*>(h)[i] =
        *reinterpret_cast<const float4*>(hsrc + (size_t)r * K + k0 + q * 4);
  }
  __syncthreads();
  const int nb = n0 + tid * 4;
  if (nb < N) {
    const float* wp = W + (size_t)k0 * N + nb;
    if (nb + 3 < N) {
      float4 acc[8];
#pragma unroll
      for (int r = 0; r < 8; ++r) acc[r] = make_float4(0.f, 0.f, 0.f, 0.f);
      for (int kk = 0; kk < BK; kk += 8) {
        float4 w[8];
#pragma unroll
        for (int j = 0; j < 8; ++j)
          w[j] = *reinterpret_cast<const float4*>(wp + (size_t)(kk + j) * N);
#pragma unroll
        for (int j = 0; j < 8; ++j) {
#pragma unroll
          for (int r = 0; r < 8; ++r) {
            float hv = h[r * BK + kk + j];
            acc[r].x += hv * w[j].x; acc[r].y += hv * w[j].y;
            acc[r].z += hv * w[j].z; acc[r].w += hv * w[j].w;
          }
        }
      }
#pragma unroll
      for (int r = 0; r < 8; ++r)
        *reinterpret_cast<float4*>(pout + (size_t)r * NPAD + nb) = acc[r];
    } else {
      for (int c = 0; c < 4; ++c) {
        if (nb + c >= N) break;
        float acc[8] = {0.f, 0.f, 0.f, 0.f, 0.f, 0.f, 0.f, 0.f};
        for (int kk = 0; kk < BK; ++kk) {
          float w = wp[(size_t)kk * N + c];
#pragma unroll
          for (int r = 0; r < 8; ++r) acc[r] += h[r * BK + kk] * w;
        }
#pragma unroll
        for (int r = 0; r < 8; ++r) pout[(size_t)r * NPAD + nb + c] = acc[r];
      }
    }
  }
  __syncthreads();
}

__global__ __launch_bounds__(256, 1) void mega(MegaP P) {
  const int bid = blockIdx.x, tid = threadIdx.x;
  float* ws = P.ws;
  unsigned* bar = (unsigned*)(ws + BARRF);
  __shared__ float sm[2608];
  const int tix0 = P.tix[0];
  const int tixc = tix0 < 0 ? 0 : (tix0 > 255 ? 255 : tix0);
  const int T = tixc + 1;
  const float4* astv = (const float4*)P.ast_in;
  float4* oastv = (float4*)P.out_ast;
  int bs = 0;

  // ================= phase E: embed + mask-detect + copy slice 0 =================
  if (bid < 8) {
    float* tmp = sm;
    int b = bid;
    const float* te = P.etok + (size_t)P.prev[0] * NE;
    const float* pe = P.epos + (size_t)tixc * NE;
    float4 t4 = *reinterpret_cast<const float4*>(te + tid * 4);
    float4 p4 = *reinterpret_cast<const float4*>(pe + tid * 4);
    float4 v = make_float4(t4.x + p4.x, t4.y + p4.y, t4.z + p4.z, t4.w + p4.w);
    float s = v.x + v.y + v.z + v.w;
    float ss = v.x * v.x + v.y * v.y + v.z * v.z + v.w * v.w;
    block_red2(s, ss, tmp);
    float m = s / NE, rs = rsqrtf(ss / NE - m * m + EPSF);
    float4 sc4 = *reinterpret_cast<const float4*>(P.lnemb_s + tid * 4);
    float4 bi = *reinterpret_cast<const float4*>(P.lnemb_b + tid * 4);
    float4 x;
    x.x = (v.x - m) * rs * sc4.x + bi.x; x.y = (v.y - m) * rs * sc4.y + bi.y;
    x.z = (v.z - m) * rs * sc4.z + bi.z; x.w = (v.w - m) * rs * sc4.w + bi.w;
    *reinterpret_cast<float4*>(ws + XBUF + (size_t)b * NE + tid * 4) = x;
    float s2 = x.x + x.y + x.z + x.w;
    float ss2 = x.x * x.x + x.y * x.y + x.z * x.z + x.w * x.w;
    block_red2(s2, ss2, tmp);
    float m2 = s2 / NE, rs2 = rsqrtf(ss2 / NE - m2 * m2 + EPSF);
    float4 b2 = *reinterpret_cast<const float4*>(P.psb + tid * 4);
    float4 o;
    o.x = (x.x - m2) * rs2 + b2.x; o.y = (x.y - m2) * rs2 + b2.y;
    o.z = (x.z - m2) * rs2 + b2.z; o.w = (x.w - m2) * rs2 + b2.w;
    *reinterpret_cast<float4*>(ws + DH1 + (size_t)b * NE + tid * 4) = o;
  } else {
    if (bid == 8) {
      int* f = (int*)sm;
      if (tid == 0) *f = 1;
      __syncthreads();
      if (tid < 128) { if (((const unsigned*)P.mask)[tid] > 1u) *f = 0; }
      __syncthreads();
      if (tid == 0)
        __hip_atomic_store(&bar[48], (*f) ? 1u : 2u, __ATOMIC_RELAXED, __HIP_MEMORY_SCOPE_AGENT);
    }
    copy_slice(astv, oastv, 0, 8, 248, tixc);
  }
  gbar(bar + bs++);

  for (int l = 0; l < NL; ++l) {
    const size_t wE = (size_t)l * NE * NE;
    const size_t wG = (size_t)l * NE * NG;
    const float* ast_l = P.ast_in + (size_t)l * 16 * NIMG * NE;
    float* oast_l = P.out_ast + (size_t)l * 16 * NIMG * NE;

    // ============ phase A: qkv partials (96 blocks) ============
    if (bid < 96) {
      int m = bid >> 5, ks = bid & 31;
      const float* W = (m == 0) ? P.Wsk + wE : (m == 1) ? P.Wsv + wE : P.Wsq + wE;
      mv_unit(W, ws + DH1, ws + P_QKV + (size_t)(m * 32 + ks) * 8192,
              1024, 1024, 1024, 32, ks * 32, 0, sm);
    }
    gbar(bar + bs++);

    // ============ phase B: qkv-reduce + self-attn + @Wso (128 blocks) ============
    if (bid < 128) {
      int b = bid >> 4, hh = bid & 15;
      float* qv = sm;            // 64
      float* kf = sm + 64;       // 64
      float* vf = sm + 128;      // 64
      float* scb = sm + 192;     // 256
      float* red = sm + 448;     // 256
      float* pv = sm + 704;      // 1024
      float* ov = sm + 1728;     // 64
      if (tid < 192) {
        int m = tid >> 6, d = tid & 63;
        const float* bp = ws + P_QKV + (size_t)(m * 32) * 8192 + (size_t)b * 1024 + hh * 64 + d;
        float acc = 0.f;
#pragma unroll
        for (int ks = 0; ks < 32; ++ks) acc += bp[(size_t)ks * 8192];
        if (m == 2) qv[d] = acc * 0.125f;
        else {
          if (m == 0) kf[d] = acc; else vf[d] = acc;
          int row = (m == 0) ? b : 8 + b;
          oast_l[((size_t)row * NIMG + tixc) * NE + hh * 64 + d] = acc;
        }
      }
      __syncthreads();
      float sj = -INFINITY;
      if (tid < T) {
        const float* kr = (tid == tixc) ? kf : (ast_l + ((size_t)b * NIMG + tid) * NE + hh * 64);
        float s = 0.f;
#pragma unroll
        for (int d0 = 0; d0 < 64; d0 += 4) {
          float4 k4 = *reinterpret_cast<const float4*>(kr + d0);
          s += qv[d0] * k4.x + qv[d0 + 1] * k4.y + qv[d0 + 2] * k4.z + qv[d0 + 3] * k4.w;
        }
        sj = s;
      }
      red[tid] = sj; __syncthreads();
      for (int o = 128; o; o >>= 1) { if (tid < o) red[tid] = fmaxf(red[tid], red[tid + o]); __syncthreads(); }
      float mx = red[0]; __syncthreads();
      float e = (tid < T) ? __expf(sj - mx) : 0.f;
      red[tid] = e; __syncthreads();
      for (int o = 128; o; o >>= 1) { if (tid < o) red[tid] += red[tid + o]; __syncthreads(); }
      float inv = 1.f / red[0];
      scb[tid] = e * inv;
      __syncthreads();
      {
        int c = tid >> 4, d4 = (tid & 15) * 4;
        float4 a = make_float4(0.f, 0.f, 0.f, 0.f);
        for (int j = c; j < T; j += 16) {
          const float* vr = (j == tixc) ? vf : (ast_l + ((size_t)(8 + b) * NIMG + j) * NE + hh * 64);
          float4 v4 = *reinterpret_cast<const float4*>(vr + d4);
          float w = scb[j];
          a.x += w * v4.x; a.y += w * v4.y; a.z += w * v4.z; a.w += w * v4.w;
        }
        pv[c * 64 + d4 + 0] = a.x; pv[c * 64 + d4 + 1] = a.y;
        pv[c * 64 + d4 + 2] = a.z; pv[c * 64 + d4 + 3] = a.w;
      }
      __syncthreads();
      if (tid < 64) {
        float s = 0.f;
#pragma unroll
        for (int c = 0; c < 16; ++c) s += pv[c * 64 + tid];
        ov[tid] = s;
      }
      __syncthreads();
      {
        int nb = tid * 4;
        const float* wp = P.Wso + wE + (size_t)(hh * 64) * NE + nb;
        float4 acc = make_float4(0.f, 0.f, 0.f, 0.f);
        for (int d = 0; d < 64; d += 8) {
          float4 w[8];
#pragma unroll
          for (int j = 0; j < 8; ++j)
            w[j] = *reinterpret_cast<const float4*>(wp + (size_t)(d + j) * NE);
#pragma unroll
          for (int j = 0; j < 8; ++j) {
            float o = ov[d + j];
            acc.x += o * w[j].x; acc.y += o * w[j].y; acc.z += o * w[j].z; acc.w += o * w[j].w;
          }
        }
        *reinterpret_cast<float4*>(ws + SSPART + ((size_t)hh * 8 + b) * 1024 + nb) = acc;
      }
    } else {
      copy_slice(astv, oastv, l * 5 + 1, 128, 128, tixc);
    }
    gbar(bar + bs++);

    // ============ phase C: x2/h2 LN + full cross-attn (128 blocks) ============
    if (bid < 128) {
      int b = bid >> 4, hh = bid & 15;
      float* vecA = sm;          // 1024
      float* vecB = sm + 1024;   // 1024
      float* red = sm + 2048;    // 256
      float* w_ = sm + 2304;     // 64
      float* qv = sm + 2368;     // 64
      float* oe = sm + 2432;     // 64
      float* tmp = sm + 2496;    // 8
      int mi32 = ((unsigned*)(ws + BARRF))[48] == 1u;
      {  // x2 = x + LN(sum SSPART; sls,slb); h2 = LN(x2)+peb -> vecA
        int col = tid * 4;
        float4 sv = make_float4(0.f, 0.f, 0.f, 0.f);
        const float* base = ws + SSPART + (size_t)b * 1024 + col;
#pragma unroll
        for (int h = 0; h < 16; h += 8) {
          float4 w[8];
#pragma unroll
          for (int j = 0; j < 8; ++j)
            w[j] = *reinterpret_cast<const float4*>(base + (size_t)(h + j) * 8192);
#pragma unroll
          for (int j = 0; j < 8; ++j) sv = f4add(sv, w[j]);
        }
        float s = sv.x + sv.y + sv.z + sv.w;
        float ss = sv.x * sv.x + sv.y * sv.y + sv.z * sv.z + sv.w * sv.w;
        block_red2(s, ss, tmp);
        float m1 = s / NE, rs1 = rsqrtf(ss / NE - m1 * m1 + EPSF);
        float4 xv = *reinterpret_cast<const float4*>(ws + XBUF + (size_t)b * NE + col);
        float4 sc1 = *reinterpret_cast<const float4*>(P.sls + (size_t)l * NE + col);
        float4 b1 = *reinterpret_cast<const float4*>(P.slb + (size_t)l * NE + col);
        float4 v;
        v.x = xv.x + (sv.x - m1) * rs1 * sc1.x + b1.x;
        v.y = xv.y + (sv.y - m1) * rs1 * sc1.y + b1.y;
        v.z = xv.z + (sv.z - m1) * rs1 * sc1.z + b1.z;
        v.w = xv.w + (sv.w - m1) * rs1 * sc1.w + b1.w;
        if (hh == 0)
          *reinterpret_cast<float4*>(ws + DX2 + (size_t)b * NE + col) = v;
        float s2 = v.x + v.y + v.z + v.w;
        float ss2 = v.x * v.x + v.y * v.y + v.z * v.z + v.w * v.w;
        block_red2(s2, ss2, tmp);
        float m2 = s2 / NE, rs2 = rsqrtf(ss2 / NE - m2 * m2 + EPSF);
        float4 b2 = *reinterpret_cast<const float4*>(P.peb + (size_t)l * NE + col);
        float4 o;
        o.x = (v.x - m2) * rs2 + b2.x; o.y = (v.y - m2) * rs2 + b2.y;
        o.z = (v.z - m2) * rs2 + b2.z; o.w = (v.w - m2) * rs2 + b2.w;
        reinterpret_cast<float4*>(vecA)[tid] = o;
      }
      __syncthreads();

      {  // qe[d] = sum_e h2[e] * Weq[e, hh*64+d]
        int d4 = (tid & 15) * 4, ech = tid >> 4;
        const float* base = P.Weq + wE + hh * 64 + d4;
        float4 a = make_float4(0.f, 0.f, 0.f, 0.f);
        for (int e = ech * 64; e < ech * 64 + 64; e += 8) {
          float4 w[8];
#pragma unroll
          for (int j = 0; j < 8; ++j)
            w[j] = *reinterpret_cast<const float4*>(base + (size_t)(e + j) * NE);
#pragma unroll
          for (int j = 0; j < 8; ++j) {
            float hv = vecA[e + j];
            a.x += hv * w[j].x; a.y += hv * w[j].y; a.z += hv * w[j].z; a.w += hv * w[j].w;
          }
        }
        vecB[ech * 64 + d4 + 0] = a.x; vecB[ech * 64 + d4 + 1] = a.y;
        vecB[ech * 64 + d4 + 2] = a.z; vecB[ech * 64 + d4 + 3] = a.w;
      }
      __syncthreads();
      if (tid < 64) {
        float s = 0.f;
#pragma unroll
        for (int c = 0; c < 16; ++c) s += vecB[c * 64 + tid];
        qv[tid] = s;
      }
      __syncthreads();

      {  // qW[e] = sum_d qv[d] * Wek[e, hh*64+d]
        float qwtmp[4];
#pragma unroll
        for (int jj = 0; jj < 4; ++jj) {
          int e = tid + 256 * jj;
          const float* wr = P.Wek + wE + (size_t)e * NE + hh * 64;
          float a = 0.f;
#pragma unroll
          for (int d0 = 0; d0 < 64; d0 += 4) {
            float4 w4 = *reinterpret_cast<const float4*>(wr + d0);
            a += qv[d0] * w4.x + qv[d0 + 1] * w4.y + qv[d0 + 2] * w4.z + qv[d0 + 3] * w4.w;
          }
          qwtmp[jj] = a;
        }
#pragma unroll
        for (int jj = 0; jj < 4; ++jj) vecB[tid + 256 * jj] = qwtmp[jj];
      }
      __syncthreads();

      {  // scores
        int t = tid & 63, ec = tid >> 6;
        const float* xr = P.enc + ((size_t)b * NTT + t) * NE + ec * 256;
        float part = 0.f;
#pragma unroll 4
        for (int i = 0; i < 256; i += 4) {
          float4 x4 = *reinterpret_cast<const float4*>(xr + i);
          part += vecB[ec * 256 + i] * x4.x + vecB[ec * 256 + i + 1] * x4.y +
                  vecB[ec * 256 + i + 2] * x4.z + vecB[ec * 256 + i + 3] * x4.w;
        }
        red[ec * 64 + t] = part;
      }
      __syncthreads();
      float sco = -INFINITY;
      if (tid < 64) {
        float s = (red[tid] + red[64 + tid] + red[128 + tid] + red[192 + tid]) * 0.125f;
        int idx = b * NTT + tid;
        bool valid = mi32 ? (((const int*)P.mask)[idx] != 0)
                          : (((const unsigned char*)P.mask)[idx] != 0);
        sco = valid ? s : -INFINITY;
      }
      __syncthreads();
      red[tid] = (tid < 64) ? sco : -INFINITY; __syncthreads();
      for (int o = 128; o; o >>= 1) { if (tid < o) red[tid] = fmaxf(red[tid], red[tid + o]); __syncthreads(); }
      float mx = red[0]; __syncthreads();
      float e = (tid < 64) ? __expf(sco - mx) : 0.f;
      red[tid] = e; __syncthreads();
      for (int o = 128; o; o >>= 1) { if (tid < o) red[tid] += red[tid + o]; __syncthreads(); }
      if (tid < 64) w_[tid] = e / red[0];
      __syncthreads();

      {  // wX[e] = sum_t w_[t] * X[b,t,e]
        float4 a = make_float4(0.f, 0.f, 0.f, 0.f);
        const float* xb = P.enc + (size_t)b * NTT * NE + tid * 4;
        for (int t = 0; t < NTT; t += 4) {
#pragma unroll
          for (int j = 0; j < 4; ++j) {
            float4 x4 = *reinterpret_cast<const float4*>(xb + (size_t)(t + j) * NE);
            float w = w_[t + j];
            a.x += w * x4.x; a.y += w * x4.y; a.z += w * x4.z; a.w += w * x4.w;
          }
        }
        reinterpret_cast<float4*>(vecA)[tid] = a;
      }
      __syncthreads();

      {  // oe[d] = sum_e wX[e] * Wev[e, hh*64+d]
        int d4 = (tid & 15) * 4, ech = tid >> 4;
        const float* base = P.Wev + wE + hh * 64 + d4;
        float4 a = make_float4(0.f, 0.f, 0.f, 0.f);
        for (int e = ech * 64; e < ech * 64 + 64; e += 8) {
          float4 w[8];
#pragma unroll
          for (int j = 0; j < 8; ++j)
            w[j] = *reinterpret_cast<const float4*>(base + (size_t)(e + j) * NE);
#pragma unroll
          for (int j = 0; j < 8; ++j) {
            float hv = vecA[e + j];
            a.x += hv * w[j].x; a.y += hv * w[j].y; a.z += hv * w[j].z; a.w += hv * w[j].w;
          }
        }
        vecB[ech * 64 + d4 + 0] = a.x; vecB[ech * 64 + d4 + 1] = a.y;
        vecB[ech * 64 + d4 + 2] = a.z; vecB[ech * 64 + d4 + 3] = a.w;
      }
      __syncthreads();
      if (tid < 64) {
        float s = 0.f;
#pragma unroll
        for (int c = 0; c < 16; ++c) s += vecB[c * 64 + tid];
        oe[tid] = s;
      }
      __syncthreads();

      {  // SEPART[hh][b] = oe @ Weo
        int nb = tid * 4;
        const float* wp = P.Weo + wE + (size_t)(hh * 64) * NE + nb;
        float4 acc = make_float4(0.f, 0.f, 0.f, 0.f);
        for (int d = 0; d < 64; d += 8) {
          float4 w[8];
#pragma unroll
          for (int j = 0; j < 8; ++j)
            w[j] = *reinterpret_cast<const float4*>(wp + (size_t)(d + j) * NE);
#pragma unroll
          for (int j = 0; j < 8; ++j) {
            float o = oe[d + j];
            acc.x += o * w[j].x; acc.y += o * w[j].y; acc.z += o * w[j].z; acc.w += o * w[j].w;
          }
        }
        *reinterpret_cast<float4*>(ws + SEPART + ((size_t)hh * 8 + b) * 1024 + nb) = acc;
      }
    } else {
      copy_slice(astv, oastv, l * 5 + 2, 128, 128, tixc);
    }
    gbar(bar + bs++);

    // ============ phase D: x3 = x2 + LN(sum SEPART); h3 (8 blocks) ============
    if (bid < 8) {
      float* tmp = sm;
      int b = bid, col = tid * 4;
      float4 sv = make_float4(0.f, 0.f, 0.f, 0.f);
      const float* base = ws + SEPART + (size_t)b * 1024 + col;
#pragma unroll
      for (int h = 0; h < 16; h += 8) {
        float4 w[8];
#pragma unroll
        for (int j = 0; j < 8; ++j)
          w[j] = *reinterpret_cast<const float4*>(base + (size_t)(h + j) * 8192);
#pragma unroll
        for (int j = 0; j < 8; ++j) sv = f4add(sv, w[j]);
      }
      float s = sv.x + sv.y + sv.z + sv.w;
      float ss = sv.x * sv.x + sv.y * sv.y + sv.z * sv.z + sv.w * sv.w;
      block_red2(s, ss, tmp);
      float m1 = s / NE, rs1 = rsqrtf(ss / NE - m1 * m1 + EPSF);
      float4 xv = *reinterpret_cast<const float4*>(ws + DX2 + (size_t)b * NE + col);
      float4 sc1 = *reinterpret_cast<const float4*>(P.els + (size_t)l * NE + col);
      float4 b1 = *reinterpret_cast<const float4*>(P.elb + (size_t)l * NE + col);
      float4 v;
      v.x = xv.x + (sv.x - m1) * rs1 * sc1.x + b1.x;
      v.y = xv.y + (sv.y - m1) * rs1 * sc1.y + b1.y;
      v.z = xv.z + (sv.z - m1) * rs1 * sc1.z + b1.z;
      v.w = xv.w + (sv.w - m1) * rs1 * sc1.w + b1.w;
      *reinterpret_cast<float4*>(ws + DX3 + (size_t)b * NE + col) = v;
      float s2 = v.x + v.y + v.z + v.w;
      float ss2 = v.x * v.x + v.y * v.y + v.z * v.z + v.w * v.w;
      block_red2(s2, ss2, tmp);
      float m2 = s2 / NE, rs2 = rsqrtf(ss2 / NE - m2 * m2 + EPSF);
      float4 b2 = *reinterpret_cast<const float4*>(P.g0b + (size_t)l * NE + col);
      float4 o;
      o.x = (v.x - m2) * rs2 + b2.x; o.y = (v.y - m2) * rs2 + b2.y;
      o.z = (v.z - m2) * rs2 + b2.z; o.w = (v.w - m2) * rs2 + b2.w;
      *reinterpret_cast<float4*>(ws + DH3 + (size_t)b * NE + col) = o;
    } else {
      copy_slice(astv, oastv, l * 5 + 3, 8, 248, tixc);
    }
    gbar(bar + bs++);

    // ============ phase F: fc0/fc1 partials (128 blocks) ============
    if (bid < 128) {
      int m = bid >> 6, rem = bid & 63, ks = rem >> 2, cb = rem & 3;
      const float* W = m ? (P.Wf1 + wG) : (P.Wf0 + wG);
      mv_unit(W, ws + DH3, ws + P_FC01 + (size_t)(m * 16 + ks) * 32768,
              1024, 4096, 4096, 64, ks * 64, cb * 1024, sm);
    }
    gbar(bar + bs++);

    // ============ phase G: hg = LN(gelu(sumA)*sumB)+g1b (8 blocks) ============
    if (bid < 8) {
      float* tmp = sm;
      int b = bid;
      float4 g[4];
      float s = 0.f, ss = 0.f;
#pragma unroll
      for (int q = 0; q < 4; ++q) {
        int col = (tid + 256 * q) * 4;
        float4 a = make_float4(0.f, 0.f, 0.f, 0.f);
        float4 bb = make_float4(0.f, 0.f, 0.f, 0.f);
        const float* baseA = ws + P_FC01 + (size_t)b * 4096 + col;
        const float* baseB = ws + P_FC01 + (size_t)(16 * 8 + b) * 4096 + col;
#pragma unroll
        for (int ks = 0; ks < 16; ++ks) {
          a = f4add(a, *reinterpret_cast<const float4*>(baseA + (size_t)ks * 32768));
          bb = f4add(bb, *reinterpret_cast<const float4*>(baseB + (size_t)ks * 32768));
        }
        float4 gg;
        gg.x = 0.5f * a.x * (1.f + erff(a.x * 0.70710678118f)) * bb.x;
        gg.y = 0.5f * a.y * (1.f + erff(a.y * 0.70710678118f)) * bb.y;
        gg.z = 0.5f * a.z * (1.f + erff(a.z * 0.70710678118f)) * bb.z;
        gg.w = 0.5f * a.w * (1.f + erff(a.w * 0.70710678118f)) * bb.w;
        g[q] = gg;
        s += gg.x + gg.y + gg.z + gg.w;
        ss += gg.x * gg.x + gg.y * gg.y + gg.z * gg.z + gg.w * gg.w;
      }
      block_red2(s, ss, tmp);
      float m = s / NG, rs = rsqrtf(ss / NG - m * m + EPSF);
#pragma unroll
      for (int q = 0; q < 4; ++q) {
        int col = (tid + 256 * q) * 4;
        float4 bi = *reinterpret_cast<const float4*>(P.g1b + (size_t)l * NG + col);
        float4 o;
        o.x = (g[q].x - m) * rs + bi.x; o.y = (g[q].y - m) * rs + bi.y;
        o.z = (g[q].z - m) * rs + bi.z; o.w = (g[q].w - m) * rs + bi.w;
        *reinterpret_cast<float4*>(ws + DHG + (size_t)b * NG + col) = o;
      }
    } else {
      copy_slice(astv, oastv, l * 5 + 4, 8, 248, tixc);
    }
    gbar(bar + bs++);

    // ============ phase H: fc2 partials (64 blocks) ============
    if (bid < 64) {
      mv_unit(P.Wf2 + (size_t)l * NG * NE, ws + DHG, ws + P_FC2 + (size_t)bid * 8192,
              4096, 1024, 1024, 64, bid * 64, 0, sm);
    }
    gbar(bar + bs++);

    // ============ phase I: x_{l+1} = x3 + sum fc2; h1/hf (8 blocks) ============
    if (bid < 8) {
      float* tmp = sm;
      int b = bid, col = tid * 4;
      float4 acc = *reinterpret_cast<const float4*>(ws + DX3 + (size_t)b * NE + col);
      const float* base = ws + P_FC2 + (size_t)b * 1024 + col;
      for (int ks = 0; ks < 64; ks += 8) {
        float4 w[8];
#pragma unroll
        for (int j = 0; j < 8; ++j)
          w[j] = *reinterpret_cast<const float4*>(base + (size_t)(ks + j) * 8192);
#pragma unroll
        for (int j = 0; j < 8; ++j) acc = f4add(acc, w[j]);
      }
      *reinterpret_cast<float4*>(ws + XBUF + (size_t)b * NE + col) = acc;
      float s = acc.x + acc.y + acc.z + acc.w;
      float ss = acc.x * acc.x + acc.y * acc.y + acc.z * acc.z + acc.w * acc.w;
      block_red2(s, ss, tmp);
      float m = s / NE, rs = rsqrtf(ss / NE - m * m + EPSF);
      const float* bias = (l < 3) ? (P.psb + (size_t)(l + 1) * NE) : P.flb;
      float* hout = (l < 3) ? (ws + DH1) : (ws + DHF);
      float4 bi = *reinterpret_cast<const float4*>(bias + col);
      float4 o;
      o.x = (acc.x - m) * rs + bi.x; o.y = (acc.y - m) * rs + bi.y;
      o.z = (acc.z - m) * rs + bi.z; o.w = (acc.w - m) * rs + bi.w;
      *reinterpret_cast<float4*>(hout + (size_t)b * NE + col) = o;
    } else {
      copy_slice(astv, oastv, l * 5 + 5, 8, 248, tixc);
    }
    gbar(bar + bs++);
  }

  // ============ phase J: lm_head partials (136 blocks, BK=128) ============
  if (bid < 136) {
    int ks = bid / 17, cb = bid % 17;
    mv_unit(P.Wlm, ws + DHF, ws + P_LM + (size_t)ks * 8 * NVPAD,
            1024, NV, NVPAD, 128, ks * 128, cb * 1024, sm);
  }
  gbar(bar + bs++);

  // ============ phase K: reduce logits (136 blocks) ============
  if (bid < 136) {
    int r = bid / 17, cc = bid % 17;
    int col = cc * 1024 + tid * 4;
    if (col < NV) {
      if (col + 3 < NV) {
        const float* base = ws + P_LM + (size_t)r * NVPAD + col;
        float4 acc = make_float4(0.f, 0.f, 0.f, 0.f);
#pragma unroll
        for (int ks = 0; ks < 8; ++ks)
          acc = f4add(acc, *reinterpret_cast<const float4*>(base + (size_t)ks * 8 * NVPAD));
        *reinterpret_cast<float4*>(P.logits + (size_t)r * NV + col) = acc;
      } else {
        for (int c = 0; c < 4 && col + c < NV; ++c) {
          float a = 0.f;
          for (int ks = 0; ks < 8; ++ks) a += ws[P_LM + ((size_t)ks * 8 + r) * NVPAD + col + c];
          P.logits[(size_t)r * NV + col + c] = a;
        }
      }
    }
  }
}

extern "C" void kernel_launch(void* const* d_in, const int* in_sizes, int n_in,
                              void* d_out, int out_size, void* d_ws, size_t ws_size,
                              hipStream_t stream) {
  MegaP P;
  P.enc = (const float*)d_in[0];
  P.ast_in = (const float*)d_in[1];
  P.mask = d_in[2];
  P.prev = (const int*)d_in[3];
  P.tix = (const int*)d_in[4];
  P.etok = (const float*)d_in[5];
  P.epos = (const float*)d_in[6];
  P.lnemb_s = (const float*)d_in[7];
  P.lnemb_b = (const float*)d_in[8];
  P.psb = (const float*)d_in[9];
  P.Wsq = (const float*)d_in[10];
  P.Wsk = (const float*)d_in[11];
  P.Wsv = (const float*)d_in[12];
  P.Wso = (const float*)d_in[13];
  P.sls = (const float*)d_in[14];
  P.slb = (const float*)d_in[15];
  P.peb = (const float*)d_in[16];
  P.Weq = (const float*)d_in[17];
  P.Wek = (const float*)d_in[18];
  P.Wev = (const float*)d_in[19];
  P.Weo = (const float*)d_in[20];
  P.els = (const float*)d_in[21];
  P.elb = (const float*)d_in[22];
  P.g0b = (const float*)d_in[23];
  P.Wf0 = (const float*)d_in[24];
  P.Wf1 = (const float*)d_in[25];
  P.g1b = (const float*)d_in[26];
  P.Wf2 = (const float*)d_in[27];
  P.flb = (const float*)d_in[28];
  P.Wlm = (const float*)d_in[29];
  P.logits = (float*)d_out;
  P.out_ast = P.logits + (size_t)NB * NV;
  P.ws = (float*)d_ws;

  // zero the barrier slots + mask flag (64 uints)
  hipMemsetAsync((char*)d_ws + (size_t)BARRF * sizeof(float), 0, 64 * sizeof(unsigned), stream);
  mega<<<NBLK, 256, 0, stream>>>(P);
}

// Round 7
// 1524.885 us; speedup vs baseline: 2.5689x; 2.5689x over previous
//
#include <hip/hip_runtime.h>
#include <math.h>

#define EPSF 1e-6f

#define NL 4
#define NB 8
#define NE 1024
#define NH 16
#define NG 4096
#define NIMG 256
#define NTT 64
#define NV 16385
#define NVPAD 17408
#define NBLK 256
#define NSLICE 21

// ---- ws float offsets ----
#define P_QKV   0          // [3][32][8][1024]
#define P_FC01  786432     // [2][16][8][4096]
#define P_FC2   1835008    // [64][8][1024]
#define P_LM    2359296    // [8][8][17408]
#define SSPART  3473408    // [16][8][1024]
#define SEPART  3604480    // [16][8][1024]
#define XBUF    3735552    // [8][1024]
#define DH1     3743744
#define DX2     3751936
#define DX3     3760128
#define DH3     3768320
#define DHG     3776512    // [8][4096]
#define DHF     3809280
#define BARRF   3817472    // 64 uints (barrier slots + mask flag @48)

struct MegaP {
  const float *enc, *ast_in;
  const void* mask;
  const int *prev, *tix;
  const float *etok, *epos, *lnemb_s, *lnemb_b;
  const float *psb, *Wsq, *Wsk, *Wsv, *Wso, *sls, *slb, *peb;
  const float *Weq, *Wek, *Wev, *Weo, *els, *elb;
  const float *g0b, *Wf0, *Wf1, *g1b, *Wf2, *flb, *Wlm;
  float *logits, *out_ast, *ws;
};

__device__ inline void wave_red2(float& a, float& b) {
#pragma unroll
  for (int o = 32; o; o >>= 1) { a += __shfl_xor(a, o); b += __shfl_xor(b, o); }
}

__device__ inline void block_red2(float& s, float& ss, float* tmp) {
  wave_red2(s, ss);
  int wv = threadIdx.x >> 6, ln = threadIdx.x & 63;
  if (ln == 0) { tmp[wv] = s; tmp[4 + wv] = ss; }
  __syncthreads();
  s = tmp[0] + tmp[1] + tmp[2] + tmp[3];
  ss = tmp[4] + tmp[5] + tmp[6] + tmp[7];
  __syncthreads();
}

__device__ inline float4 f4add(float4 a, float4 b) {
  return make_float4(a.x + b.x, a.y + b.y, a.z + b.z, a.w + b.w);
}

// device-scope grid barrier (one monotonic slot per phase, memset to 0 per call).
// Arrive: RELEASE fetch_add (1 L2 writeback). Poll: RELAXED loads (bypass L2,
// NO per-poll cache invalidate). Depart: one ACQUIRE load (1 invalidate).
__device__ inline void gbar(unsigned* slot) {
  __syncthreads();
  if (threadIdx.x == 0) {
    __hip_atomic_fetch_add(slot, 1u, __ATOMIC_RELEASE, __HIP_MEMORY_SCOPE_AGENT);
    while (__hip_atomic_load(slot, __ATOMIC_RELAXED, __HIP_MEMORY_SCOPE_AGENT) < (unsigned)NBLK) {
      __builtin_amdgcn_s_sleep(4);
    }
    (void)__hip_atomic_load(slot, __ATOMIC_ACQUIRE, __HIP_MEMORY_SCOPE_AGENT);
  }
  __syncthreads();
}

// copy a slice of attention_state passthrough, skipping row==tixc (written fresh)
__device__ inline void copy_slice(const float4* __restrict__ src, float4* __restrict__ dst,
                                  int idx, int bid0, int nidle, int tixc) {
  const int n4 = NL * 16 * NIMG * (NE / 4);
  const int CH = (n4 + NSLICE - 1) / NSLICE;
  int s = idx * CH, e = s + CH; if (e > n4) e = n4;
  for (int i = s + (blockIdx.x - bid0) * 256 + (int)threadIdx.x; i < e; i += nidle * 256) {
    int row = (i >> 8) & 255;
    if (row != tixc) dst[i] = src[i];
  }
}

// one matvec work unit: pout[8][NPAD] (cols n0..n0+1023) = h(8xBK from hsrc@k0) @ W
__device__ void mv_unit(const float* __restrict__ W, const float* __restrict__ hsrc,
                        float* __restrict__ pout, int K, int N, int NPAD,
                        int BK, int k0, int n0, float* h) {
  const int tid = threadIdx.x;
  const int bk4 = BK >> 2;
  for (int i = tid; i < 8 * bk4; i += 256) {
    int r = i / bk4, q = i - r * bk4;
    reinterpret_cast<float4*>(h)[i] =
        *reinterpret_cast<const float4*>(hsrc + (size_t)r * K + k0 + q * 4);
  }
  __syncthreads();
  const int nb = n0 + tid * 4;
  if (nb < N) {
    const float* wp = W + (size_t)k0 * N + nb;
    if (nb + 3 < N) {
      float4 acc[8];
#pragma unroll
      for (int r = 0; r < 8; ++r) acc[r] = make_float4(0.f, 0.f, 0.f, 0.f);
      for (int kk = 0; kk < BK; kk += 8) {
        float4 w[8];
#pragma unroll
        for (int j = 0; j < 8; ++j)
          w[j] = *reinterpret_cast<const float4*>(wp + (size_t)(kk + j) * N);
#pragma unroll
        for (int j = 0; j < 8; ++j) {
#pragma unroll
          for (int r = 0; r < 8; ++r) {
            float hv = h[r * BK + kk + j];
            acc[r].x += hv * w[j].x; acc[r].y += hv * w[j].y;
            acc[r].z += hv * w[j].z; acc[r].w += hv * w[j].w;
          }
        }
      }
#pragma unroll
      for (int r = 0; r < 8; ++r)
        *reinterpret_cast<float4*>(pout + (size_t)r * NPAD + nb) = acc[r];
    } else {
      for (int c = 0; c < 4; ++c) {
        if (nb + c >= N) break;
        float acc[8] = {0.f, 0.f, 0.f, 0.f, 0.f, 0.f, 0.f, 0.f};
        for (int kk = 0; kk < BK; ++kk) {
          float w = wp[(size_t)kk * N + c];
#pragma unroll
          for (int r = 0; r < 8; ++r) acc[r] += h[r * BK + kk] * w;
        }
#pragma unroll
        for (int r = 0; r < 8; ++r) pout[(size_t)r * NPAD + nb + c] = acc[r];
      }
    }
  }
  __syncthreads();
}

__global__ __launch_bounds__(256, 1) void mega(MegaP P) {
  const int bid = blockIdx.x, tid = threadIdx.x;
  float* ws = P.ws;
  unsigned* bar = (unsigned*)(ws + BARRF);
  __shared__ float sm[2608];
  const int tix0 = P.tix[0];
  const int tixc = tix0 < 0 ? 0 : (tix0 > 255 ? 255 : tix0);
  const int T = tixc + 1;
  const float4* astv = (const float4*)P.ast_in;
  float4* oastv = (float4*)P.out_ast;
  int bs = 0;

  // ================= phase E: embed + mask-detect + copy slice 0 =================
  if (bid < 8) {
    float* tmp = sm;
    int b = bid;
    const float* te = P.etok + (size_t)P.prev[0] * NE;
    const float* pe = P.epos + (size_t)tixc * NE;
    float4 t4 = *reinterpret_cast<const float4*>(te + tid * 4);
    float4 p4 = *reinterpret_cast<const float4*>(pe + tid * 4);
    float4 v = make_float4(t4.x + p4.x, t4.y + p4.y, t4.z + p4.z, t4.w + p4.w);
    float s = v.x + v.y + v.z + v.w;
    float ss = v.x * v.x + v.y * v.y + v.z * v.z + v.w * v.w;
    block_red2(s, ss, tmp);
    float m = s / NE, rs = rsqrtf(ss / NE - m * m + EPSF);
    float4 sc4 = *reinterpret_cast<const float4*>(P.lnemb_s + tid * 4);
    float4 bi = *reinterpret_cast<const float4*>(P.lnemb_b + tid * 4);
    float4 x;
    x.x = (v.x - m) * rs * sc4.x + bi.x; x.y = (v.y - m) * rs * sc4.y + bi.y;
    x.z = (v.z - m) * rs * sc4.z + bi.z; x.w = (v.w - m) * rs * sc4.w + bi.w;
    *reinterpret_cast<float4*>(ws + XBUF + (size_t)b * NE + tid * 4) = x;
    float s2 = x.x + x.y + x.z + x.w;
    float ss2 = x.x * x.x + x.y * x.y + x.z * x.z + x.w * x.w;
    block_red2(s2, ss2, tmp);
    float m2 = s2 / NE, rs2 = rsqrtf(ss2 / NE - m2 * m2 + EPSF);
    float4 b2 = *reinterpret_cast<const float4*>(P.psb + tid * 4);
    float4 o;
    o.x = (x.x - m2) * rs2 + b2.x; o.y = (x.y - m2) * rs2 + b2.y;
    o.z = (x.z - m2) * rs2 + b2.z; o.w = (x.w - m2) * rs2 + b2.w;
    *reinterpret_cast<float4*>(ws + DH1 + (size_t)b * NE + tid * 4) = o;
  } else {
    if (bid == 8) {
      int* f = (int*)sm;
      if (tid == 0) *f = 1;
      __syncthreads();
      if (tid < 128) { if (((const unsigned*)P.mask)[tid] > 1u) *f = 0; }
      __syncthreads();
      if (tid == 0)
        __hip_atomic_store(&bar[48], (*f) ? 1u : 2u, __ATOMIC_RELAXED, __HIP_MEMORY_SCOPE_AGENT);
    }
    copy_slice(astv, oastv, 0, 8, 248, tixc);
  }
  gbar(bar + bs++);

  for (int l = 0; l < NL; ++l) {
    const size_t wE = (size_t)l * NE * NE;
    const size_t wG = (size_t)l * NE * NG;
    const float* ast_l = P.ast_in + (size_t)l * 16 * NIMG * NE;
    float* oast_l = P.out_ast + (size_t)l * 16 * NIMG * NE;

    // ============ phase A: qkv partials (96 blocks) ============
    if (bid < 96) {
      int m = bid >> 5, ks = bid & 31;
      const float* W = (m == 0) ? P.Wsk + wE : (m == 1) ? P.Wsv + wE : P.Wsq + wE;
      mv_unit(W, ws + DH1, ws + P_QKV + (size_t)(m * 32 + ks) * 8192,
              1024, 1024, 1024, 32, ks * 32, 0, sm);
    }
    gbar(bar + bs++);

    // ============ phase B: qkv-reduce + self-attn + @Wso (128 blocks) ============
    if (bid < 128) {
      int b = bid >> 4, hh = bid & 15;
      float* qv = sm;            // 64
      float* kf = sm + 64;       // 64
      float* vf = sm + 128;      // 64
      float* scb = sm + 192;     // 256
      float* red = sm + 448;     // 256
      float* pv = sm + 704;      // 1024
      float* ov = sm + 1728;     // 64
      if (tid < 192) {
        int m = tid >> 6, d = tid & 63;
        const float* bp = ws + P_QKV + (size_t)(m * 32) * 8192 + (size_t)b * 1024 + hh * 64 + d;
        float acc = 0.f;
#pragma unroll
        for (int ks = 0; ks < 32; ++ks) acc += bp[(size_t)ks * 8192];
        if (m == 2) qv[d] = acc * 0.125f;
        else {
          if (m == 0) kf[d] = acc; else vf[d] = acc;
          int row = (m == 0) ? b : 8 + b;
          oast_l[((size_t)row * NIMG + tixc) * NE + hh * 64 + d] = acc;
        }
      }
      __syncthreads();
      float sj = -INFINITY;
      if (tid < T) {
        const float* kr = (tid == tixc) ? kf : (ast_l + ((size_t)b * NIMG + tid) * NE + hh * 64);
        float s = 0.f;
#pragma unroll
        for (int d0 = 0; d0 < 64; d0 += 4) {
          float4 k4 = *reinterpret_cast<const float4*>(kr + d0);
          s += qv[d0] * k4.x + qv[d0 + 1] * k4.y + qv[d0 + 2] * k4.z + qv[d0 + 3] * k4.w;
        }
        sj = s;
      }
      red[tid] = sj; __syncthreads();
      for (int o = 128; o; o >>= 1) { if (tid < o) red[tid] = fmaxf(red[tid], red[tid + o]); __syncthreads(); }
      float mx = red[0]; __syncthreads();
      float e = (tid < T) ? __expf(sj - mx) : 0.f;
      red[tid] = e; __syncthreads();
      for (int o = 128; o; o >>= 1) { if (tid < o) red[tid] += red[tid + o]; __syncthreads(); }
      float inv = 1.f / red[0];
      scb[tid] = e * inv;
      __syncthreads();
      {
        int c = tid >> 4, d4 = (tid & 15) * 4;
        float4 a = make_float4(0.f, 0.f, 0.f, 0.f);
        for (int j = c; j < T; j += 16) {
          const float* vr = (j == tixc) ? vf : (ast_l + ((size_t)(8 + b) * NIMG + j) * NE + hh * 64);
          float4 v4 = *reinterpret_cast<const float4*>(vr + d4);
          float w = scb[j];
          a.x += w * v4.x; a.y += w * v4.y; a.z += w * v4.z; a.w += w * v4.w;
        }
        pv[c * 64 + d4 + 0] = a.x; pv[c * 64 + d4 + 1] = a.y;
        pv[c * 64 + d4 + 2] = a.z; pv[c * 64 + d4 + 3] = a.w;
      }
      __syncthreads();
      if (tid < 64) {
        float s = 0.f;
#pragma unroll
        for (int c = 0; c < 16; ++c) s += pv[c * 64 + tid];
        ov[tid] = s;
      }
      __syncthreads();
      {
        int nb = tid * 4;
        const float* wp = P.Wso + wE + (size_t)(hh * 64) * NE + nb;
        float4 acc = make_float4(0.f, 0.f, 0.f, 0.f);
        for (int d = 0; d < 64; d += 8) {
          float4 w[8];
#pragma unroll
          for (int j = 0; j < 8; ++j)
            w[j] = *reinterpret_cast<const float4*>(wp + (size_t)(d + j) * NE);
#pragma unroll
          for (int j = 0; j < 8; ++j) {
            float o = ov[d + j];
            acc.x += o * w[j].x; acc.y += o * w[j].y; acc.z += o * w[j].z; acc.w += o * w[j].w;
          }
        }
        *reinterpret_cast<float4*>(ws + SSPART + ((size_t)hh * 8 + b) * 1024 + nb) = acc;
      }
    } else {
      copy_slice(astv, oastv, l * 5 + 1, 128, 128, tixc);
    }
    gbar(bar + bs++);

    // ============ phase C: x2/h2 LN + full cross-attn (128 blocks) ============
    if (bid < 128) {
      int b = bid >> 4, hh = bid & 15;
      float* vecA = sm;          // 1024
      float* vecB = sm + 1024;   // 1024
      float* red = sm + 2048;    // 256
      float* w_ = sm + 2304;     // 64
      float* qv = sm + 2368;     // 64
      float* oe = sm + 2432;     // 64
      float* tmp = sm + 2496;    // 8
      int mi32 = ((unsigned*)(ws + BARRF))[48] == 1u;
      {  // x2 = x + LN(sum SSPART; sls,slb); h2 = LN(x2)+peb -> vecA
        int col = tid * 4;
        float4 sv = make_float4(0.f, 0.f, 0.f, 0.f);
        const float* base = ws + SSPART + (size_t)b * 1024 + col;
#pragma unroll
        for (int h = 0; h < 16; h += 8) {
          float4 w[8];
#pragma unroll
          for (int j = 0; j < 8; ++j)
            w[j] = *reinterpret_cast<const float4*>(base + (size_t)(h + j) * 8192);
#pragma unroll
          for (int j = 0; j < 8; ++j) sv = f4add(sv, w[j]);
        }
        float s = sv.x + sv.y + sv.z + sv.w;
        float ss = sv.x * sv.x + sv.y * sv.y + sv.z * sv.z + sv.w * sv.w;
        block_red2(s, ss, tmp);
        float m1 = s / NE, rs1 = rsqrtf(ss / NE - m1 * m1 + EPSF);
        float4 xv = *reinterpret_cast<const float4*>(ws + XBUF + (size_t)b * NE + col);
        float4 sc1 = *reinterpret_cast<const float4*>(P.sls + (size_t)l * NE + col);
        float4 b1 = *reinterpret_cast<const float4*>(P.slb + (size_t)l * NE + col);
        float4 v;
        v.x = xv.x + (sv.x - m1) * rs1 * sc1.x + b1.x;
        v.y = xv.y + (sv.y - m1) * rs1 * sc1.y + b1.y;
        v.z = xv.z + (sv.z - m1) * rs1 * sc1.z + b1.z;
        v.w = xv.w + (sv.w - m1) * rs1 * sc1.w + b1.w;
        if (hh == 0)
          *reinterpret_cast<float4*>(ws + DX2 + (size_t)b * NE + col) = v;
        float s2 = v.x + v.y + v.z + v.w;
        float ss2 = v.x * v.x + v.y * v.y + v.z * v.z + v.w * v.w;
        block_red2(s2, ss2, tmp);
        float m2 = s2 / NE, rs2 = rsqrtf(ss2 / NE - m2 * m2 + EPSF);
        float4 b2 = *reinterpret_cast<const float4*>(P.peb + (size_t)l * NE + col);
        float4 o;
        o.x = (v.x - m2) * rs2 + b2.x; o.y = (v.y - m2) * rs2 + b2.y;
        o.z = (v.z - m2) * rs2 + b2.z; o.w = (v.w - m2) * rs2 + b2.w;
        reinterpret_cast<float4*>(vecA)[tid] = o;
      }
      __syncthreads();

      {  // qe[d] = sum_e h2[e] * Weq[e, hh*64+d]
        int d4 = (tid & 15) * 4, ech = tid >> 4;
        const float* base = P.Weq + wE + hh * 64 + d4;
        float4 a = make_float4(0.f, 0.f, 0.f, 0.f);
        for (int e = ech * 64; e < ech * 64 + 64; e += 8) {
          float4 w[8];
#pragma unroll
          for (int j = 0; j < 8; ++j)
            w[j] = *reinterpret_cast<const float4*>(base + (size_t)(e + j) * NE);
#pragma unroll
          for (int j = 0; j < 8; ++j) {
            float hv = vecA[e + j];
            a.x += hv * w[j].x; a.y += hv * w[j].y; a.z += hv * w[j].z; a.w += hv * w[j].w;
          }
        }
        vecB[ech * 64 + d4 + 0] = a.x; vecB[ech * 64 + d4 + 1] = a.y;
        vecB[ech * 64 + d4 + 2] = a.z; vecB[ech * 64 + d4 + 3] = a.w;
      }
      __syncthreads();
      if (tid < 64) {
        float s = 0.f;
#pragma unroll
        for (int c = 0; c < 16; ++c) s += vecB[c * 64 + tid];
        qv[tid] = s;
      }
      __syncthreads();

      {  // qW[e] = sum_d qv[d] * Wek[e, hh*64+d]
        float qwtmp[4];
#pragma unroll
        for (int jj = 0; jj < 4; ++jj) {
          int e = tid + 256 * jj;
          const float* wr = P.Wek + wE + (size_t)e * NE + hh * 64;
          float a = 0.f;
#pragma unroll
          for (int d0 = 0; d0 < 64; d0 += 4) {
            float4 w4 = *reinterpret_cast<const float4*>(wr + d0);
            a += qv[d0] * w4.x + qv[d0 + 1] * w4.y + qv[d0 + 2] * w4.z + qv[d0 + 3] * w4.w;
          }
          qwtmp[jj] = a;
        }
#pragma unroll
        for (int jj = 0; jj < 4; ++jj) vecB[tid + 256 * jj] = qwtmp[jj];
      }
      __syncthreads();

      {  // scores
        int t = tid & 63, ec = tid >> 6;
        const float* xr = P.enc + ((size_t)b * NTT + t) * NE + ec * 256;
        float part = 0.f;
#pragma unroll 4
        for (int i = 0; i < 256; i += 4) {
          float4 x4 = *reinterpret_cast<const float4*>(xr + i);
          part += vecB[ec * 256 + i] * x4.x + vecB[ec * 256 + i + 1] * x4.y +
                  vecB[ec * 256 + i + 2] * x4.z + vecB[ec * 256 + i + 3] * x4.w;
        }
        red[ec * 64 + t] = part;
      }
      __syncthreads();
      float sco = -INFINITY;
      if (tid < 64) {
        float s = (red[tid] + red[64 + tid] + red[128 + tid] + red[192 + tid]) * 0.125f;
        int idx = b * NTT + tid;
        bool valid = mi32 ? (((const int*)P.mask)[idx] != 0)
                          : (((const unsigned char*)P.mask)[idx] != 0);
        sco = valid ? s : -INFINITY;
      }
      __syncthreads();
      red[tid] = (tid < 64) ? sco : -INFINITY; __syncthreads();
      for (int o = 128; o; o >>= 1) { if (tid < o) red[tid] = fmaxf(red[tid], red[tid + o]); __syncthreads(); }
      float mx = red[0]; __syncthreads();
      float e = (tid < 64) ? __expf(sco - mx) : 0.f;
      red[tid] = e; __syncthreads();
      for (int o = 128; o; o >>= 1) { if (tid < o) red[tid] += red[tid + o]; __syncthreads(); }
      if (tid < 64) w_[tid] = e / red[0];
      __syncthreads();

      {  // wX[e] = sum_t w_[t] * X[b,t,e]
        float4 a = make_float4(0.f, 0.f, 0.f, 0.f);
        const float* xb = P.enc + (size_t)b * NTT * NE + tid * 4;
        for (int t = 0; t < NTT; t += 4) {
#pragma unroll
          for (int j = 0; j < 4; ++j) {
            float4 x4 = *reinterpret_cast<const float4*>(xb + (size_t)(t + j) * NE);
            float w = w_[t + j];
            a.x += w * x4.x; a.y += w * x4.y; a.z += w * x4.z; a.w += w * x4.w;
          }
        }
        reinterpret_cast<float4*>(vecA)[tid] = a;
      }
      __syncthreads();

      {  // oe[d] = sum_e wX[e] * Wev[e, hh*64+d]
        int d4 = (tid & 15) * 4, ech = tid >> 4;
        const float* base = P.Wev + wE + hh * 64 + d4;
        float4 a = make_float4(0.f, 0.f, 0.f, 0.f);
        for (int e = ech * 64; e < ech * 64 + 64; e += 8) {
          float4 w[8];
#pragma unroll
          for (int j = 0; j < 8; ++j)
            w[j] = *reinterpret_cast<const float4*>(base + (size_t)(e + j) * NE);
#pragma unroll
          for (int j = 0; j < 8; ++j) {
            float hv = vecA[e + j];
            a.x += hv * w[j].x; a.y += hv * w[j].y; a.z += hv * w[j].z; a.w += hv * w[j].w;
          }
        }
        vecB[ech * 64 + d4 + 0] = a.x; vecB[ech * 64 + d4 + 1] = a.y;
        vecB[ech * 64 + d4 + 2] = a.z; vecB[ech * 64 + d4 + 3] = a.w;
      }
      __syncthreads();
      if (tid < 64) {
        float s = 0.f;
#pragma unroll
        for (int c = 0; c < 16; ++c) s += vecB[c * 64 + tid];
        oe[tid] = s;
      }
      __syncthreads();

      {  // SEPART[hh][b] = oe @ Weo
        int nb = tid * 4;
        const float* wp = P.Weo + wE + (size_t)(hh * 64) * NE + nb;
        float4 acc = make_float4(0.f, 0.f, 0.f, 0.f);
        for (int d = 0; d < 64; d += 8) {
          float4 w[8];
#pragma unroll
          for (int j = 0; j < 8; ++j)
            w[j] = *reinterpret_cast<const float4*>(wp + (size_t)(d + j) * NE);
#pragma unroll
          for (int j = 0; j < 8; ++j) {
            float o = oe[d + j];
            acc.x += o * w[j].x; acc.y += o * w[j].y; acc.z += o * w[j].z; acc.w += o * w[j].w;
          }
        }
        *reinterpret_cast<float4*>(ws + SEPART + ((size_t)hh * 8 + b) * 1024 + nb) = acc;
      }
    } else {
      copy_slice(astv, oastv, l * 5 + 2, 128, 128, tixc);
    }
    gbar(bar + bs++);

    // ============ phase D: x3 = x2 + LN(sum SEPART); h3 (8 blocks) ============
    if (bid < 8) {
      float* tmp = sm;
      int b = bid, col = tid * 4;
      float4 sv = make_float4(0.f, 0.f, 0.f, 0.f);
      const float* base = ws + SEPART + (size_t)b * 1024 + col;
#pragma unroll
      for (int h = 0; h < 16; h += 8) {
        float4 w[8];
#pragma unroll
        for (int j = 0; j < 8; ++j)
          w[j] = *reinterpret_cast<const float4*>(base + (size_t)(h + j) * 8192);
#pragma unroll
        for (int j = 0; j < 8; ++j) sv = f4add(sv, w[j]);
      }
      float s = sv.x + sv.y + sv.z + sv.w;
      float ss = sv.x * sv.x + sv.y * sv.y + sv.z * sv.z + sv.w * sv.w;
      block_red2(s, ss, tmp);
      float m1 = s / NE, rs1 = rsqrtf(ss / NE - m1 * m1 + EPSF);
      float4 xv = *reinterpret_cast<const float4*>(ws + DX2 + (size_t)b * NE + col);
      float4 sc1 = *reinterpret_cast<const float4*>(P.els + (size_t)l * NE + col);
      float4 b1 = *reinterpret_cast<const float4*>(P.elb + (size_t)l * NE + col);
      float4 v;
      v.x = xv.x + (sv.x - m1) * rs1 * sc1.x + b1.x;
      v.y = xv.y + (sv.y - m1) * rs1 * sc1.y + b1.y;
      v.z = xv.z + (sv.z - m1) * rs1 * sc1.z + b1.z;
      v.w = xv.w + (sv.w - m1) * rs1 * sc1.w + b1.w;
      *reinterpret_cast<float4*>(ws + DX3 + (size_t)b * NE + col) = v;
      float s2 = v.x + v.y + v.z + v.w;
      float ss2 = v.x * v.x + v.y * v.y + v.z * v.z + v.w * v.w;
      block_red2(s2, ss2, tmp);
      float m2 = s2 / NE, rs2 = rsqrtf(ss2 / NE - m2 * m2 + EPSF);
      float4 b2 = *reinterpret_cast<const float4*>(P.g0b + (size_t)l * NE + col);
      float4 o;
      o.x = (v.x - m2) * rs2 + b2.x; o.y = (v.y - m2) * rs2 + b2.y;
      o.z = (v.z - m2) * rs2 + b2.z; o.w = (v.w - m2) * rs2 + b2.w;
      *reinterpret_cast<float4*>(ws + DH3 + (size_t)b * NE + col) = o;
    } else {
      copy_slice(astv, oastv, l * 5 + 3, 8, 248, tixc);
    }
    gbar(bar + bs++);

    // ============ phase F: fc0/fc1 partials (128 blocks) ============
    if (bid < 128) {
      int m = bid >> 6, rem = bid & 63, ks = rem >> 2, cb = rem & 3;
      const float* W = m ? (P.Wf1 + wG) : (P.Wf0 + wG);
      mv_unit(W, ws + DH3, ws + P_FC01 + (size_t)(m * 16 + ks) * 32768,
              1024, 4096, 4096, 64, ks * 64, cb * 1024, sm);
    }
    gbar(bar + bs++);

    // ============ phase G: hg = LN(gelu(sumA)*sumB)+g1b (8 blocks) ============
    if (bid < 8) {
      float* tmp = sm;
      int b = bid;
      float4 g[4];
      float s = 0.f, ss = 0.f;
#pragma unroll
      for (int q = 0; q < 4; ++q) {
        int col = (tid + 256 * q) * 4;
        float4 a = make_float4(0.f, 0.f, 0.f, 0.f);
        float4 bb = make_float4(0.f, 0.f, 0.f, 0.f);
        const float* baseA = ws + P_FC01 + (size_t)b * 4096 + col;
        const float* baseB = ws + P_FC01 + (size_t)(16 * 8 + b) * 4096 + col;
#pragma unroll
        for (int ks = 0; ks < 16; ++ks) {
          a = f4add(a, *reinterpret_cast<const float4*>(baseA + (size_t)ks * 32768));
          bb = f4add(bb, *reinterpret_cast<const float4*>(baseB + (size_t)ks * 32768));
        }
        float4 gg;
        gg.x = 0.5f * a.x * (1.f + erff(a.x * 0.70710678118f)) * bb.x;
        gg.y = 0.5f * a.y * (1.f + erff(a.y * 0.70710678118f)) * bb.y;
        gg.z = 0.5f * a.z * (1.f + erff(a.z * 0.70710678118f)) * bb.z;
        gg.w = 0.5f * a.w * (1.f + erff(a.w * 0.70710678118f)) * bb.w;
        g[q] = gg;
        s += gg.x + gg.y + gg.z + gg.w;
        ss += gg.x * gg.x + gg.y * gg.y + gg.z * gg.z + gg.w * gg.w;
      }
      block_red2(s, ss, tmp);
      float m = s / NG, rs = rsqrtf(ss / NG - m * m + EPSF);
#pragma unroll
      for (int q = 0; q < 4; ++q) {
        int col = (tid + 256 * q) * 4;
        float4 bi = *reinterpret_cast<const float4*>(P.g1b + (size_t)l * NG + col);
        float4 o;
        o.x = (g[q].x - m) * rs + bi.x; o.y = (g[q].y - m) * rs + bi.y;
        o.z = (g[q].z - m) * rs + bi.z; o.w = (g[q].w - m) * rs + bi.w;
        *reinterpret_cast<float4*>(ws + DHG + (size_t)b * NG + col) = o;
      }
    } else {
      copy_slice(astv, oastv, l * 5 + 4, 8, 248, tixc);
    }
    gbar(bar + bs++);

    // ============ phase H: fc2 partials (64 blocks) ============
    if (bid < 64) {
      mv_unit(P.Wf2 + (size_t)l * NG * NE, ws + DHG, ws + P_FC2 + (size_t)bid * 8192,
              4096, 1024, 1024, 64, bid * 64, 0, sm);
    }
    gbar(bar + bs++);

    // ============ phase I: x_{l+1} = x3 + sum fc2; h1/hf (8 blocks) ============
    if (bid < 8) {
      float* tmp = sm;
      int b = bid, col = tid * 4;
      float4 acc = *reinterpret_cast<const float4*>(ws + DX3 + (size_t)b * NE + col);
      const float* base = ws + P_FC2 + (size_t)b * 1024 + col;
      for (int ks = 0; ks < 64; ks += 8) {
        float4 w[8];
#pragma unroll
        for (int j = 0; j < 8; ++j)
          w[j] = *reinterpret_cast<const float4*>(base + (size_t)(ks + j) * 8192);
#pragma unroll
        for (int j = 0; j < 8; ++j) acc = f4add(acc, w[j]);
      }
      *reinterpret_cast<float4*>(ws + XBUF + (size_t)b * NE + col) = acc;
      float s = acc.x + acc.y + acc.z + acc.w;
      float ss = acc.x * acc.x + acc.y * acc.y + acc.z * acc.z + acc.w * acc.w;
      block_red2(s, ss, tmp);
      float m = s / NE, rs = rsqrtf(ss / NE - m * m + EPSF);
      const float* bias = (l < 3) ? (P.psb + (size_t)(l + 1) * NE) : P.flb;
      float* hout = (l < 3) ? (ws + DH1) : (ws + DHF);
      float4 bi = *reinterpret_cast<const float4*>(bias + col);
      float4 o;
      o.x = (acc.x - m) * rs + bi.x; o.y = (acc.y - m) * rs + bi.y;
      o.z = (acc.z - m) * rs + bi.z; o.w = (acc.w - m) * rs + bi.w;
      *reinterpret_cast<float4*>(hout + (size_t)b * NE + col) = o;
    } else {
      copy_slice(astv, oastv, l * 5 + 5, 8, 248, tixc);
    }
    gbar(bar + bs++);
  }

  // ============ phase J: lm_head partials (136 blocks, BK=128) ============
  if (bid < 136) {
    int ks = bid / 17, cb = bid % 17;
    mv_unit(P.Wlm, ws + DHF, ws + P_LM + (size_t)ks * 8 * NVPAD,
            1024, NV, NVPAD, 128, ks * 128, cb * 1024, sm);
  }
  gbar(bar + bs++);

  // ============ phase K: reduce logits (136 blocks) ============
  if (bid < 136) {
    int r = bid / 17, cc = bid % 17;
    int col = cc * 1024 + tid * 4;
    if (col < NV) {
      if (col + 3 < NV) {
        const float* base = ws + P_LM + (size_t)r * NVPAD + col;
        float4 acc = make_float4(0.f, 0.f, 0.f, 0.f);
#pragma unroll
        for (int ks = 0; ks < 8; ++ks)
          acc = f4add(acc, *reinterpret_cast<const float4*>(base + (size_t)ks * 8 * NVPAD));
        *reinterpret_cast<float4*>(P.logits + (size_t)r * NV + col) = acc;
      } else {
        for (int c = 0; c < 4 && col + c < NV; ++c) {
          float a = 0.f;
          for (int ks = 0; ks < 8; ++ks) a += ws[P_LM + ((size_t)ks * 8 + r) * NVPAD + col + c];
          P.logits[(size_t)r * NV + col + c] = a;
        }
      }
    }
  }
}

extern "C" void kernel_launch(void* const* d_in, const int* in_sizes, int n_in,
                              void* d_out, int out_size, void* d_ws, size_t ws_size,
                              hipStream_t stream) {
  MegaP P;
  P.enc = (const float*)d_in[0];
  P.ast_in = (const float*)d_in[1];
  P.mask = d_in[2];
  P.prev = (const int*)d_in[3];
  P.tix = (const int*)d_in[4];
  P.etok = (const float*)d_in[5];
  P.epos = (const float*)d_in[6];
  P.lnemb_s = (const float*)d_in[7];
  P.lnemb_b = (const float*)d_in[8];
  P.psb = (const float*)d_in[9];
  P.Wsq = (const float*)d_in[10];
  P.Wsk = (const float*)d_in[11];
  P.Wsv = (const float*)d_in[12];
  P.Wso = (const float*)d_in[13];
  P.sls = (const float*)d_in[14];
  P.slb = (const float*)d_in[15];
  P.peb = (const float*)d_in[16];
  P.Weq = (const float*)d_in[17];
  P.Wek = (const float*)d_in[18];
  P.Wev = (const float*)d_in[19];
  P.Weo = (const float*)d_in[20];
  P.els = (const float*)d_in[21];
  P.elb = (const float*)d_in[22];
  P.g0b = (const float*)d_in[23];
  P.Wf0 = (const float*)d_in[24];
  P.Wf1 = (const float*)d_in[25];
  P.g1b = (const float*)d_in[26];
  P.Wf2 = (const float*)d_in[27];
  P.flb = (const float*)d_in[28];
  P.Wlm = (const float*)d_in[29];
  P.logits = (float*)d_out;
  P.out_ast = P.logits + (size_t)NB * NV;
  P.ws = (float*)d_ws;

  // zero the barrier slots + mask flag (64 uints)
  hipMemsetAsync((char*)d_ws + (size_t)BARRF * sizeof(float), 0, 64 * sizeof(unsigned), stream);
  mega<<<NBLK, 256, 0, stream>>>(P);
}

// Round 8
// 570.521 us; speedup vs baseline: 6.8661x; 2.6728x over previous
//
#include <hip/hip_runtime.h>
#include <math.h>

#define EPSF 1e-6f

#define NL 4
#define NB 8
#define NE 1024
#define NH 16
#define NG 4096
#define NIMG 256
#define NTT 64
#define NV 16385
#define NVPAD 17408

// ---- workspace float offsets (no zeroing needed; all plain stores) ----
#define P_QKV   0          // [3][32][8][1024]
#define P_FC01  786432     // [2][16][8][4096]
#define P_FC2   1835008    // [64][8][1024]
#define P_LM    2359296    // [16][8][17408]
#define SSPART  4587520    // [16][8][1024]
#define SEPART  4718592    // [16][8][1024]
#define XBUF    4849664    // [8][1024]
#define DH1     4857856
#define DX2     4866048
#define DX3     4874240
#define DH3     4882432
#define DHG     4890624    // [8][4096]
#define DHF     4923392
#define MFLAG   4931584    // 1 uint: 1=int32 mask, 2=uint8 mask

__device__ inline void wave_red2(float& a, float& b) {
#pragma unroll
  for (int o = 32; o; o >>= 1) { a += __shfl_xor(a, o); b += __shfl_xor(b, o); }
}

__device__ inline void block_red2(float& s, float& ss, float* tmp) {
  wave_red2(s, ss);
  int wv = threadIdx.x >> 6, ln = threadIdx.x & 63;
  if (ln == 0) { tmp[wv] = s; tmp[4 + wv] = ss; }
  __syncthreads();
  s = tmp[0] + tmp[1] + tmp[2] + tmp[3];
  ss = tmp[4] + tmp[5] + tmp[6] + tmp[7];
  __syncthreads();
}

__device__ inline float4 f4add(float4 a, float4 b) {
  return make_float4(a.x + b.x, a.y + b.y, a.z + b.z, a.w + b.w);
}

// ---------------- streaming matvec to K-split partials ----------------
struct MvPartP {
  const float* W0; const float* W1; const float* W2;
  float* pout;
  const float* hsrc;   // [8][K], LN already applied
  int K, N, NPAD, CB, KS;
};

__global__ __launch_bounds__(256) void mv_part(MvPartP p) {
  __shared__ float h[8 * 64];
  const int tid = threadIdx.x;
  const int per = p.CB * p.KS;
  const int m = blockIdx.x / per, rem = blockIdx.x % per;
  const int ks = rem / p.CB, cb = rem % p.CB;
  const int BK = p.K / p.KS;
  const int k0 = ks * BK;
  const int n0 = cb * 1024;
  const int bk4 = BK >> 2;
  for (int i = tid; i < 8 * bk4; i += 256) {
    int r = i / bk4, q = i - r * bk4;
    reinterpret_cast<float4*>(h)[i] =
        *reinterpret_cast<const float4*>(p.hsrc + (size_t)r * p.K + k0 + q * 4);
  }
  __syncthreads();

  const int nb = n0 + tid * 4;
  if (nb >= p.N) return;
  const float* W = (m == 0) ? p.W0 : (m == 1) ? p.W1 : p.W2;
  float* pr = p.pout + (size_t)(m * p.KS + ks) * 8 * p.NPAD;
  const float* wp = W + (size_t)k0 * p.N + nb;

  if (nb + 3 < p.N) {
    float4 acc[8];
#pragma unroll
    for (int r = 0; r < 8; ++r) acc[r] = make_float4(0.f, 0.f, 0.f, 0.f);
    for (int kk = 0; kk < BK; kk += 8) {
      float4 w[8];
#pragma unroll
      for (int j = 0; j < 8; ++j)
        w[j] = *reinterpret_cast<const float4*>(wp + (size_t)(kk + j) * p.N);
#pragma unroll
      for (int j = 0; j < 8; ++j) {
#pragma unroll
        for (int r = 0; r < 8; ++r) {
          float hv = h[r * BK + kk + j];
          acc[r].x += hv * w[j].x; acc[r].y += hv * w[j].y;
          acc[r].z += hv * w[j].z; acc[r].w += hv * w[j].w;
        }
      }
    }
#pragma unroll
    for (int r = 0; r < 8; ++r)
      *reinterpret_cast<float4*>(pr + (size_t)r * p.NPAD + nb) = acc[r];
  } else {
    for (int c = 0; c < 4; ++c) {
      if (nb + c >= p.N) break;
      float acc[8] = {0.f, 0.f, 0.f, 0.f, 0.f, 0.f, 0.f, 0.f};
      for (int kk = 0; kk < BK; ++kk) {
        float w = wp[(size_t)kk * p.N + c];
#pragma unroll
        for (int r = 0; r < 8; ++r) acc[r] += h[r * BK + kk] * w;
      }
#pragma unroll
      for (int r = 0; r < 8; ++r) pr[(size_t)r * p.NPAD + nb + c] = acc[r];
    }
  }
}

// ---------------- embed (blocks 0-7) + mask-detect (block 8) + ast copy ----------------
__global__ __launch_bounds__(256) void embed_copy(const float* __restrict__ tok,
    const float* __restrict__ pos, const int* __restrict__ prev, const int* __restrict__ tixp,
    const float* __restrict__ lnb, const float* __restrict__ lns,
    const float* __restrict__ psb0, const void* __restrict__ maskp,
    float* __restrict__ x0, float* __restrict__ h1, unsigned* __restrict__ mflag,
    const float4* __restrict__ astv, float4* __restrict__ oastv) {
  __shared__ float tmp[8];
  int bid = blockIdx.x, tid = threadIdx.x;
  if (bid < 8) {
    int b = bid;
    const float* te = tok + (size_t)prev[0] * NE;
    const float* pe = pos + (size_t)tixp[0] * NE;
    float4 t4 = *reinterpret_cast<const float4*>(te + tid * 4);
    float4 p4 = *reinterpret_cast<const float4*>(pe + tid * 4);
    float4 v = make_float4(t4.x + p4.x, t4.y + p4.y, t4.z + p4.z, t4.w + p4.w);
    float s = v.x + v.y + v.z + v.w;
    float ss = v.x * v.x + v.y * v.y + v.z * v.z + v.w * v.w;
    block_red2(s, ss, tmp);
    float m = s / NE, rs = rsqrtf(ss / NE - m * m + EPSF);
    float4 sc = *reinterpret_cast<const float4*>(lns + tid * 4);
    float4 bi = *reinterpret_cast<const float4*>(lnb + tid * 4);
    float4 x;
    x.x = (v.x - m) * rs * sc.x + bi.x; x.y = (v.y - m) * rs * sc.y + bi.y;
    x.z = (v.z - m) * rs * sc.z + bi.z; x.w = (v.w - m) * rs * sc.w + bi.w;
    *reinterpret_cast<float4*>(x0 + (size_t)b * NE + tid * 4) = x;
    float s2 = x.x + x.y + x.z + x.w;
    float ss2 = x.x * x.x + x.y * x.y + x.z * x.z + x.w * x.w;
    block_red2(s2, ss2, tmp);
    float m2 = s2 / NE, rs2 = rsqrtf(ss2 / NE - m2 * m2 + EPSF);
    float4 b2 = *reinterpret_cast<const float4*>(psb0 + tid * 4);
    float4 o;
    o.x = (x.x - m2) * rs2 + b2.x; o.y = (x.y - m2) * rs2 + b2.y;
    o.z = (x.z - m2) * rs2 + b2.z; o.w = (x.w - m2) * rs2 + b2.w;
    *reinterpret_cast<float4*>(h1 + (size_t)b * NE + tid * 4) = o;
    return;
  }
  if (bid == 8) {
    // parallel mask dtype detection: 128 words = 512B, in-bounds for both layouts
    __shared__ int f;
    if (tid == 0) f = 1;
    __syncthreads();
    if (tid < 128) { if (((const unsigned*)maskp)[tid] > 1u) f = 0; }
    __syncthreads();
    if (tid == 0) *mflag = f ? 1u : 2u;
  }
  // ast passthrough copy over blocks 8..4103
  const int n4 = NL * 16 * NIMG * (NE / 4);
  for (int i = (bid - 8) * 256 + tid; i < n4; i += 4096 * 256) oastv[i] = astv[i];
}

// ---------------- x_next = resid + sum_ks fc2part ; h = LN(x_next)+bias ----------------
__global__ __launch_bounds__(256) void ln_fc2(const float* __restrict__ P,
    const float* __restrict__ resid, const float* __restrict__ bias,
    float* __restrict__ xout, float* __restrict__ hout, int KS) {
  __shared__ float tmp[8];
  int b = blockIdx.x, tid = threadIdx.x;
  int col = tid * 4;
  float4 acc = *reinterpret_cast<const float4*>(resid + (size_t)b * NE + col);
  const float* base = P + (size_t)b * 1024 + col;
  for (int ks = 0; ks < KS; ks += 8) {
    float4 w[8];
#pragma unroll
    for (int j = 0; j < 8; ++j)
      w[j] = *reinterpret_cast<const float4*>(base + (size_t)(ks + j) * 8192);
#pragma unroll
    for (int j = 0; j < 8; ++j) acc = f4add(acc, w[j]);
  }
  *reinterpret_cast<float4*>(xout + (size_t)b * NE + col) = acc;
  float s = acc.x + acc.y + acc.z + acc.w;
  float ss = acc.x * acc.x + acc.y * acc.y + acc.z * acc.z + acc.w * acc.w;
  block_red2(s, ss, tmp);
  float m = s / NE, rs = rsqrtf(ss / NE - m * m + EPSF);
  float4 bi = *reinterpret_cast<const float4*>(bias + col);
  float4 o;
  o.x = (acc.x - m) * rs + bi.x; o.y = (acc.y - m) * rs + bi.y;
  o.z = (acc.z - m) * rs + bi.z; o.w = (acc.w - m) * rs + bi.w;
  *reinterpret_cast<float4*>(hout + (size_t)b * NE + col) = o;
}

// ---------------- x2 = x + LN(sum part; lns1,lnb1); h = LN(x2)+lnb2 ----------------
__global__ __launch_bounds__(256) void ln_res_sum(const float* __restrict__ xres,
    const float* __restrict__ part, const float* __restrict__ lns1,
    const float* __restrict__ lnb1, const float* __restrict__ lnb2,
    float* __restrict__ xstore, float* __restrict__ hout) {
  __shared__ float tmp[8];
  int b = blockIdx.x, tid = threadIdx.x;
  int col = tid * 4;
  float4 sv = make_float4(0.f, 0.f, 0.f, 0.f);
  const float* base = part + (size_t)b * 1024 + col;
#pragma unroll
  for (int h = 0; h < 16; h += 8) {
    float4 w[8];
#pragma unroll
    for (int j = 0; j < 8; ++j)
      w[j] = *reinterpret_cast<const float4*>(base + (size_t)(h + j) * 8192);
#pragma unroll
    for (int j = 0; j < 8; ++j) sv = f4add(sv, w[j]);
  }
  float s = sv.x + sv.y + sv.z + sv.w;
  float ss = sv.x * sv.x + sv.y * sv.y + sv.z * sv.z + sv.w * sv.w;
  block_red2(s, ss, tmp);
  float m1 = s / NE, rs1 = rsqrtf(ss / NE - m1 * m1 + EPSF);
  float4 xv = *reinterpret_cast<const float4*>(xres + (size_t)b * NE + col);
  float4 sc1 = *reinterpret_cast<const float4*>(lns1 + col);
  float4 b1 = *reinterpret_cast<const float4*>(lnb1 + col);
  float4 v;
  v.x = xv.x + (sv.x - m1) * rs1 * sc1.x + b1.x;
  v.y = xv.y + (sv.y - m1) * rs1 * sc1.y + b1.y;
  v.z = xv.z + (sv.z - m1) * rs1 * sc1.z + b1.z;
  v.w = xv.w + (sv.w - m1) * rs1 * sc1.w + b1.w;
  *reinterpret_cast<float4*>(xstore + (size_t)b * NE + col) = v;
  float s2 = v.x + v.y + v.z + v.w;
  float ss2 = v.x * v.x + v.y * v.y + v.z * v.z + v.w * v.w;
  block_red2(s2, ss2, tmp);
  float m2 = s2 / NE, rs2 = rsqrtf(ss2 / NE - m2 * m2 + EPSF);
  float4 b2 = *reinterpret_cast<const float4*>(lnb2 + col);
  float4 o;
  o.x = (v.x - m2) * rs2 + b2.x; o.y = (v.y - m2) * rs2 + b2.y;
  o.z = (v.z - m2) * rs2 + b2.z; o.w = (v.w - m2) * rs2 + b2.w;
  *reinterpret_cast<float4*>(hout + (size_t)b * NE + col) = o;
}

// ---------------- hg = LN(gelu(sumA)*sumB)+lnb (width 4096) ----------------
__global__ __launch_bounds__(256) void gelu_ln_sum(const float* __restrict__ P,
    const float* __restrict__ lnb, float* __restrict__ hout) {
  __shared__ float tmp[8];
  int b = blockIdx.x, tid = threadIdx.x;
  float4 g[4];
  float s = 0.f, ss = 0.f;
#pragma unroll
  for (int q = 0; q < 4; ++q) {
    int col = (tid + 256 * q) * 4;
    float4 a = make_float4(0.f, 0.f, 0.f, 0.f);
    float4 bb = make_float4(0.f, 0.f, 0.f, 0.f);
    const float* baseA = P + (size_t)b * 4096 + col;
    const float* baseB = P + ((size_t)16 * 8 + b) * 4096 + col;
#pragma unroll
    for (int ks = 0; ks < 16; ++ks) {
      a = f4add(a, *reinterpret_cast<const float4*>(baseA + (size_t)ks * 32768));
      bb = f4add(bb, *reinterpret_cast<const float4*>(baseB + (size_t)ks * 32768));
    }
    float4 gg;
    gg.x = 0.5f * a.x * (1.f + erff(a.x * 0.70710678118f)) * bb.x;
    gg.y = 0.5f * a.y * (1.f + erff(a.y * 0.70710678118f)) * bb.y;
    gg.z = 0.5f * a.z * (1.f + erff(a.z * 0.70710678118f)) * bb.z;
    gg.w = 0.5f * a.w * (1.f + erff(a.w * 0.70710678118f)) * bb.w;
    g[q] = gg;
    s += gg.x + gg.y + gg.z + gg.w;
    ss += gg.x * gg.x + gg.y * gg.y + gg.z * gg.z + gg.w * gg.w;
  }
  block_red2(s, ss, tmp);
  float m = s / NG, rs = rsqrtf(ss / NG - m * m + EPSF);
#pragma unroll
  for (int q = 0; q < 4; ++q) {
    int col = (tid + 256 * q) * 4;
    float4 bi = *reinterpret_cast<const float4*>(lnb + col);
    float4 o;
    o.x = (g[q].x - m) * rs + bi.x; o.y = (g[q].y - m) * rs + bi.y;
    o.z = (g[q].z - m) * rs + bi.z; o.w = (g[q].w - m) * rs + bi.w;
    *reinterpret_cast<float4*>(hout + (size_t)b * NG + col) = o;
  }
}

// ---------------- fused: qkv-reduce + fresh KV out + self-attn + @Wso ----------------
__global__ __launch_bounds__(256) void attn_fused(const float* __restrict__ Pqkv,
    const float* __restrict__ ast_l, const int* __restrict__ tixp,
    const float* __restrict__ Wso, float* __restrict__ spart, float* __restrict__ oast_l) {
  int b = blockIdx.x >> 4, hh = blockIdx.x & 15;
  int tid = threadIdx.x;
  int tix0 = tixp[0];
  int tixc = tix0 < 0 ? 0 : (tix0 > 255 ? 255 : tix0);
  int T = tixc + 1;
  __shared__ float qv[64];
  __shared__ float kf[64];
  __shared__ float vf[64];
  __shared__ float scb[256];
  __shared__ float red[256];
  __shared__ float pv[1024];
  __shared__ float ov[64];
  if (tid < 192) {
    int m = tid >> 6, d = tid & 63;
    const float* bp = Pqkv + (size_t)(m * 32) * 8192 + (size_t)b * 1024 + hh * 64 + d;
    float acc = 0.f;
#pragma unroll
    for (int ks = 0; ks < 32; ++ks) acc += bp[(size_t)ks * 8192];
    if (m == 2) qv[d] = acc * 0.125f;
    else {
      if (m == 0) kf[d] = acc; else vf[d] = acc;
      if (tix0 >= 0 && tix0 < NIMG) {
        int row = (m == 0) ? b : 8 + b;
        oast_l[((size_t)row * NIMG + tix0) * NE + hh * 64 + d] = acc;
      }
    }
  }
  __syncthreads();
  float sj = -INFINITY;
  if (tid < T) {
    const float* kr = (tid == tixc) ? kf : (ast_l + ((size_t)b * NIMG + tid) * NE + hh * 64);
    float s = 0.f;
#pragma unroll
    for (int d0 = 0; d0 < 64; d0 += 4) {
      float4 k4 = *reinterpret_cast<const float4*>(kr + d0);
      s += qv[d0] * k4.x + qv[d0 + 1] * k4.y + qv[d0 + 2] * k4.z + qv[d0 + 3] * k4.w;
    }
    sj = s;
  }
  red[tid] = sj; __syncthreads();
  for (int o = 128; o; o >>= 1) { if (tid < o) red[tid] = fmaxf(red[tid], red[tid + o]); __syncthreads(); }
  float mx = red[0]; __syncthreads();
  float e = (tid < T) ? __expf(sj - mx) : 0.f;
  red[tid] = e; __syncthreads();
  for (int o = 128; o; o >>= 1) { if (tid < o) red[tid] += red[tid + o]; __syncthreads(); }
  float inv = 1.f / red[0];
  scb[tid] = e * inv;
  __syncthreads();
  {
    int c = tid >> 4, d4 = (tid & 15) * 4;
    float4 a = make_float4(0.f, 0.f, 0.f, 0.f);
    for (int j = c; j < T; j += 16) {
      const float* vr = (j == tixc) ? vf : (ast_l + ((size_t)(8 + b) * NIMG + j) * NE + hh * 64);
      float4 v4 = *reinterpret_cast<const float4*>(vr + d4);
      float w = scb[j];
      a.x += w * v4.x; a.y += w * v4.y; a.z += w * v4.z; a.w += w * v4.w;
    }
    pv[c * 64 + d4 + 0] = a.x; pv[c * 64 + d4 + 1] = a.y;
    pv[c * 64 + d4 + 2] = a.z; pv[c * 64 + d4 + 3] = a.w;
  }
  __syncthreads();
  if (tid < 64) {
    float s = 0.f;
#pragma unroll
    for (int c = 0; c < 16; ++c) s += pv[c * 64 + tid];
    ov[tid] = s;
  }
  __syncthreads();
  {
    int nb = tid * 4;
    const float* wp = Wso + (size_t)(hh * 64) * NE + nb;
    float4 acc = make_float4(0.f, 0.f, 0.f, 0.f);
    for (int d = 0; d < 64; d += 8) {
      float4 w[8];
#pragma unroll
      for (int j = 0; j < 8; ++j)
        w[j] = *reinterpret_cast<const float4*>(wp + (size_t)(d + j) * NE);
#pragma unroll
      for (int j = 0; j < 8; ++j) {
        float o = ov[d + j];
        acc.x += o * w[j].x; acc.y += o * w[j].y; acc.z += o * w[j].z; acc.w += o * w[j].w;
      }
    }
    *reinterpret_cast<float4*>(spart + ((size_t)hh * 8 + b) * 1024 + nb) = acc;
  }
}

// ---------------- fused: x2/h2 LN + cross attention chain ----------------
__global__ __launch_bounds__(256) void cross_fused(const float* __restrict__ xres,
    const float* __restrict__ sspart, const float* __restrict__ sls,
    const float* __restrict__ slb, const float* __restrict__ peb,
    const float* __restrict__ Weq, const float* __restrict__ Wek,
    const float* __restrict__ Wev, const float* __restrict__ Weo,
    const float* __restrict__ X, const void* __restrict__ maskp,
    const unsigned* __restrict__ mflag, float* __restrict__ x2store,
    float* __restrict__ spart) {
  int b = blockIdx.x >> 4, hh = blockIdx.x & 15;
  int tid = threadIdx.x;
  __shared__ float vecA[NE];
  __shared__ float vecB[NE];
  __shared__ float red[256];
  __shared__ float w_[NTT];
  __shared__ float qv[64];
  __shared__ float oe[64];
  __shared__ float tmp[8];
  int mi32 = (*mflag == 1u);
  {  // x2 = x + LN(sum SSPART; sls,slb); h2 = LN(x2)+peb -> vecA (row b only)
    int col = tid * 4;
    float4 sv = make_float4(0.f, 0.f, 0.f, 0.f);
    const float* base = sspart + (size_t)b * 1024 + col;
#pragma unroll
    for (int h = 0; h < 16; h += 8) {
      float4 w[8];
#pragma unroll
      for (int j = 0; j < 8; ++j)
        w[j] = *reinterpret_cast<const float4*>(base + (size_t)(h + j) * 8192);
#pragma unroll
      for (int j = 0; j < 8; ++j) sv = f4add(sv, w[j]);
    }
    float s = sv.x + sv.y + sv.z + sv.w;
    float ss = sv.x * sv.x + sv.y * sv.y + sv.z * sv.z + sv.w * sv.w;
    block_red2(s, ss, tmp);
    float m1 = s / NE, rs1 = rsqrtf(ss / NE - m1 * m1 + EPSF);
    float4 xv = *reinterpret_cast<const float4*>(xres + (size_t)b * NE + col);
    float4 sc1 = *reinterpret_cast<const float4*>(sls + col);
    float4 b1 = *reinterpret_cast<const float4*>(slb + col);
    float4 v;
    v.x = xv.x + (sv.x - m1) * rs1 * sc1.x + b1.x;
    v.y = xv.y + (sv.y - m1) * rs1 * sc1.y + b1.y;
    v.z = xv.z + (sv.z - m1) * rs1 * sc1.z + b1.z;
    v.w = xv.w + (sv.w - m1) * rs1 * sc1.w + b1.w;
    if (hh == 0)
      *reinterpret_cast<float4*>(x2store + (size_t)b * NE + col) = v;
    float s2 = v.x + v.y + v.z + v.w;
    float ss2 = v.x * v.x + v.y * v.y + v.z * v.z + v.w * v.w;
    block_red2(s2, ss2, tmp);
    float m2 = s2 / NE, rs2 = rsqrtf(ss2 / NE - m2 * m2 + EPSF);
    float4 b2 = *reinterpret_cast<const float4*>(peb + col);
    float4 o;
    o.x = (v.x - m2) * rs2 + b2.x; o.y = (v.y - m2) * rs2 + b2.y;
    o.z = (v.z - m2) * rs2 + b2.z; o.w = (v.w - m2) * rs2 + b2.w;
    reinterpret_cast<float4*>(vecA)[tid] = o;
  }
  __syncthreads();

  {  // qe[d] = sum_e h2[e] * Weq[e, hh*64+d]
    int d4 = (tid & 15) * 4, ech = tid >> 4;
    const float* base = Weq + hh * 64 + d4;
    float4 a = make_float4(0.f, 0.f, 0.f, 0.f);
    for (int e = ech * 64; e < ech * 64 + 64; e += 8) {
      float4 w[8];
#pragma unroll
      for (int j = 0; j < 8; ++j)
        w[j] = *reinterpret_cast<const float4*>(base + (size_t)(e + j) * NE);
#pragma unroll
      for (int j = 0; j < 8; ++j) {
        float hv = vecA[e + j];
        a.x += hv * w[j].x; a.y += hv * w[j].y; a.z += hv * w[j].z; a.w += hv * w[j].w;
      }
    }
    vecB[ech * 64 + d4 + 0] = a.x; vecB[ech * 64 + d4 + 1] = a.y;
    vecB[ech * 64 + d4 + 2] = a.z; vecB[ech * 64 + d4 + 3] = a.w;
  }
  __syncthreads();
  if (tid < 64) {
    float s = 0.f;
#pragma unroll
    for (int c = 0; c < 16; ++c) s += vecB[c * 64 + tid];
    qv[tid] = s;
  }
  __syncthreads();

  {  // qW[e] = sum_d qv[d] * Wek[e, hh*64+d]
    float qwtmp[4];
#pragma unroll
    for (int jj = 0; jj < 4; ++jj) {
      int e = tid + 256 * jj;
      const float* wr = Wek + (size_t)e * NE + hh * 64;
      float a = 0.f;
#pragma unroll
      for (int d0 = 0; d0 < 64; d0 += 4) {
        float4 w4 = *reinterpret_cast<const float4*>(wr + d0);
        a += qv[d0] * w4.x + qv[d0 + 1] * w4.y + qv[d0 + 2] * w4.z + qv[d0 + 3] * w4.w;
      }
      qwtmp[jj] = a;
    }
#pragma unroll
    for (int jj = 0; jj < 4; ++jj) vecB[tid + 256 * jj] = qwtmp[jj];
  }
  __syncthreads();

  {  // scores[t] = 0.125 * sum_e qW[e] X[b,t,e]
    int t = tid & 63, ec = tid >> 6;
    const float* xr = X + ((size_t)b * NTT + t) * NE + ec * 256;
    float part = 0.f;
#pragma unroll 4
    for (int i = 0; i < 256; i += 4) {
      float4 x4 = *reinterpret_cast<const float4*>(xr + i);
      part += vecB[ec * 256 + i] * x4.x + vecB[ec * 256 + i + 1] * x4.y +
              vecB[ec * 256 + i + 2] * x4.z + vecB[ec * 256 + i + 3] * x4.w;
    }
    red[ec * 64 + t] = part;
  }
  __syncthreads();
  float sco = -INFINITY;
  if (tid < 64) {
    float s = (red[tid] + red[64 + tid] + red[128 + tid] + red[192 + tid]) * 0.125f;
    int idx = b * NTT + tid;
    bool valid = mi32 ? (((const int*)maskp)[idx] != 0)
                      : (((const unsigned char*)maskp)[idx] != 0);
    sco = valid ? s : -INFINITY;
  }
  __syncthreads();
  red[tid] = (tid < 64) ? sco : -INFINITY; __syncthreads();
  for (int o = 128; o; o >>= 1) { if (tid < o) red[tid] = fmaxf(red[tid], red[tid + o]); __syncthreads(); }
  float mx = red[0]; __syncthreads();
  float e = (tid < 64) ? __expf(sco - mx) : 0.f;
  red[tid] = e; __syncthreads();
  for (int o = 128; o; o >>= 1) { if (tid < o) red[tid] += red[tid + o]; __syncthreads(); }
  if (tid < 64) w_[tid] = e / red[0];
  __syncthreads();

  {  // wX[e] = sum_t w_[t] * X[b,t,e]
    float4 a = make_float4(0.f, 0.f, 0.f, 0.f);
    const float* xb = X + (size_t)b * NTT * NE + tid * 4;
    for (int t = 0; t < NTT; t += 4) {
#pragma unroll
      for (int j = 0; j < 4; ++j) {
        float4 x4 = *reinterpret_cast<const float4*>(xb + (size_t)(t + j) * NE);
        float w = w_[t + j];
        a.x += w * x4.x; a.y += w * x4.y; a.z += w * x4.z; a.w += w * x4.w;
      }
    }
    reinterpret_cast<float4*>(vecA)[tid] = a;
  }
  __syncthreads();

  {  // oe[d] = sum_e wX[e] * Wev[e, hh*64+d]
    int d4 = (tid & 15) * 4, ech = tid >> 4;
    const float* base = Wev + hh * 64 + d4;
    float4 a = make_float4(0.f, 0.f, 0.f, 0.f);
    for (int e = ech * 64; e < ech * 64 + 64; e += 8) {
      float4 w[8];
#pragma unroll
      for (int j = 0; j < 8; ++j)
        w[j] = *reinterpret_cast<const float4*>(base + (size_t)(e + j) * NE);
#pragma unroll
      for (int j = 0; j < 8; ++j) {
        float hv = vecA[e + j];
        a.x += hv * w[j].x; a.y += hv * w[j].y; a.z += hv * w[j].z; a.w += hv * w[j].w;
      }
    }
    vecB[ech * 64 + d4 + 0] = a.x; vecB[ech * 64 + d4 + 1] = a.y;
    vecB[ech * 64 + d4 + 2] = a.z; vecB[ech * 64 + d4 + 3] = a.w;
  }
  __syncthreads();
  if (tid < 64) {
    float s = 0.f;
#pragma unroll
    for (int c = 0; c < 16; ++c) s += vecB[c * 64 + tid];
    oe[tid] = s;
  }
  __syncthreads();

  {  // spart[hh][b] = oe @ Weo
    int nb = tid * 4;
    const float* wp = Weo + (size_t)(hh * 64) * NE + nb;
    float4 acc = make_float4(0.f, 0.f, 0.f, 0.f);
    for (int d = 0; d < 64; d += 8) {
      float4 w[8];
#pragma unroll
      for (int j = 0; j < 8; ++j)
        w[j] = *reinterpret_cast<const float4*>(wp + (size_t)(d + j) * NE);
#pragma unroll
      for (int j = 0; j < 8; ++j) {
        float o = oe[d + j];
        acc.x += o * w[j].x; acc.y += o * w[j].y; acc.z += o * w[j].z; acc.w += o * w[j].w;
      }
    }
    *reinterpret_cast<float4*>(spart + ((size_t)hh * 8 + b) * 1024 + nb) = acc;
  }
}

// ---------------- reduce lm_head partials -> logits ----------------
__global__ __launch_bounds__(256) void reduce_logits(const float* __restrict__ P,
                                                     float* __restrict__ logits) {
  int r = blockIdx.x / 17, cc = blockIdx.x % 17;
  int col = cc * 1024 + threadIdx.x * 4;
  if (col >= NV) return;
  if (col + 3 < NV) {
    const float* base = P + (size_t)r * NVPAD + col;
    float4 acc = make_float4(0.f, 0.f, 0.f, 0.f);
    for (int ks = 0; ks < 16; ks += 8) {
      float4 w[8];
#pragma unroll
      for (int j = 0; j < 8; ++j)
        w[j] = *reinterpret_cast<const float4*>(base + (size_t)(ks + j) * 8 * NVPAD);
#pragma unroll
      for (int j = 0; j < 8; ++j) acc = f4add(acc, w[j]);
    }
    *reinterpret_cast<float4*>(logits + (size_t)r * NV + col) = acc;
  } else {
    for (int c = 0; c < 4 && col + c < NV; ++c) {
      float a = 0.f;
      for (int ks = 0; ks < 16; ++ks) a += P[((size_t)ks * 8 + r) * NVPAD + col + c];
      logits[(size_t)r * NV + col + c] = a;
    }
  }
}

extern "C" void kernel_launch(void* const* d_in, const int* in_sizes, int n_in,
                              void* d_out, int out_size, void* d_ws, size_t ws_size,
                              hipStream_t stream) {
  const float* enc_state = (const float*)d_in[0];
  const float* ast_in    = (const float*)d_in[1];
  const void* amask      = d_in[2];
  const int* prev = (const int*)d_in[3];
  const int* tix  = (const int*)d_in[4];
  const float* embed_tok = (const float*)d_in[5];
  const float* embed_pos = (const float*)d_in[6];
  const float* lnemb_s = (const float*)d_in[7];
  const float* lnemb_b = (const float*)d_in[8];
  const float* psb = (const float*)d_in[9];
  const float* Wsq = (const float*)d_in[10];
  const float* Wsk = (const float*)d_in[11];
  const float* Wsv = (const float*)d_in[12];
  const float* Wso = (const float*)d_in[13];
  const float* sls = (const float*)d_in[14];
  const float* slb = (const float*)d_in[15];
  const float* peb = (const float*)d_in[16];
  const float* Weq = (const float*)d_in[17];
  const float* Wek = (const float*)d_in[18];
  const float* Wev = (const float*)d_in[19];
  const float* Weo = (const float*)d_in[20];
  const float* els = (const float*)d_in[21];
  const float* elb = (const float*)d_in[22];
  const float* g0b = (const float*)d_in[23];
  const float* Wf0 = (const float*)d_in[24];
  const float* Wf1 = (const float*)d_in[25];
  const float* g1b = (const float*)d_in[26];
  const float* Wf2 = (const float*)d_in[27];
  const float* flb = (const float*)d_in[28];
  const float* Wlm = (const float*)d_in[29];

  float* ws = (float*)d_ws;
  float* logits = (float*)d_out;
  float* out_ast = logits + (size_t)NB * NV;

  embed_copy<<<4104, 256, 0, stream>>>(embed_tok, embed_pos, prev, tix, lnemb_b, lnemb_s,
                                       psb, amask, ws + XBUF, ws + DH1,
                                       (unsigned*)(ws + MFLAG),
                                       (const float4*)ast_in, (float4*)out_ast);

  for (int l = 0; l < NL; ++l) {
    size_t wE = (size_t)l * NE * NE;
    size_t wG = (size_t)l * NE * NG;

    if (l > 0) {
      ln_fc2<<<NB, 256, 0, stream>>>(ws + P_FC2, ws + DX3, psb + (size_t)l * NE,
                                     ws + XBUF, ws + DH1, 64);
    }
    {  // qkv partials
      MvPartP p{}; p.W0 = Wsk + wE; p.W1 = Wsv + wE; p.W2 = Wsq + wE;
      p.pout = ws + P_QKV; p.hsrc = ws + DH1;
      p.K = NE; p.N = NE; p.NPAD = NE; p.CB = 1; p.KS = 32;
      mv_part<<<3 * 32, 256, 0, stream>>>(p);
    }
    attn_fused<<<NB * NH, 256, 0, stream>>>(ws + P_QKV,
                                            ast_in + (size_t)l * 16 * NIMG * NE, tix,
                                            Wso + wE, ws + SSPART,
                                            out_ast + (size_t)l * 16 * NIMG * NE);
    cross_fused<<<NB * NH, 256, 0, stream>>>(ws + XBUF, ws + SSPART,
                                             sls + (size_t)l * NE, slb + (size_t)l * NE,
                                             peb + (size_t)l * NE,
                                             Weq + wE, Wek + wE, Wev + wE, Weo + wE,
                                             enc_state, amask,
                                             (const unsigned*)(ws + MFLAG),
                                             ws + DX2, ws + SEPART);
    ln_res_sum<<<NB, 256, 0, stream>>>(ws + DX2, ws + SEPART, els + (size_t)l * NE,
                                       elb + (size_t)l * NE, g0b + (size_t)l * NE,
                                       ws + DX3, ws + DH3);
    {  // fc0, fc1 partials
      MvPartP p{}; p.W0 = Wf0 + wG; p.W1 = Wf1 + wG;
      p.pout = ws + P_FC01; p.hsrc = ws + DH3;
      p.K = NE; p.N = NG; p.NPAD = NG; p.CB = 4; p.KS = 16;
      mv_part<<<2 * 4 * 16, 256, 0, stream>>>(p);
    }
    gelu_ln_sum<<<NB, 256, 0, stream>>>(ws + P_FC01, g1b + (size_t)l * NG, ws + DHG);
    {  // fc2 partials
      MvPartP p{}; p.W0 = Wf2 + (size_t)l * NG * NE;
      p.pout = ws + P_FC2; p.hsrc = ws + DHG;
      p.K = NG; p.N = NE; p.NPAD = NE; p.CB = 1; p.KS = 64;
      mv_part<<<64, 256, 0, stream>>>(p);
    }
  }
  ln_fc2<<<NB, 256, 0, stream>>>(ws + P_FC2, ws + DX3, flb, ws + XBUF, ws + DHF, 64);
  {  // lm_head partials
    MvPartP p{}; p.W0 = Wlm;
    p.pout = ws + P_LM; p.hsrc = ws + DHF;
    p.K = NE; p.N = NV; p.NPAD = NVPAD; p.CB = 17; p.KS = 16;
    mv_part<<<17 * 16, 256, 0, stream>>>(p);
  }
  reduce_logits<<<NB * 17, 256, 0, stream>>>(ws + P_LM, logits);
}

// Round 9
// 480.513 us; speedup vs baseline: 8.1522x; 1.1873x over previous
//
#include <hip/hip_runtime.h>
#include <math.h>

#define EPSF 1e-6f

#define NL 4
#define NB 8
#define NE 1024
#define NH 16
#define NG 4096
#define NIMG 256
#define NTT 64
#define NV 16385
#define NVPAD 17408

// ---- workspace float offsets ----
#define P_QKV   0          // [3][16][8][1024]
#define P_FC01  393216     // [2][8][8][4096]
#define P_FC2   917504     // [32][8][1024]
#define P_LM    1179648    // [16][8][17408]
#define SSPART  3407872    // [16][8][1024]
#define SEPART  3538944    // [16][8][1024]
#define XBUF    3670016    // [8][1024]
#define DX2     3678208
#define DX3     3686400
#define DH3     3694592
#define DG      3702784    // [8][4096]
#define XSTAT   3735552    // [8][4][2]
#define GSTAT   3735616    // [8][8][2]
#define MFLAG   3735744

__device__ inline void wave_red2(float& a, float& b) {
#pragma unroll
  for (int o = 32; o; o >>= 1) { a += __shfl_xor(a, o); b += __shfl_xor(b, o); }
}

__device__ inline void block_red2(float& s, float& ss, float* tmp) {
  wave_red2(s, ss);
  int wv = threadIdx.x >> 6, ln = threadIdx.x & 63;
  if (ln == 0) { tmp[wv] = s; tmp[4 + wv] = ss; }
  __syncthreads();
  s = tmp[0] + tmp[1] + tmp[2] + tmp[3];
  ss = tmp[4] + tmp[5] + tmp[6] + tmp[7];
  __syncthreads();
}

__device__ inline float4 f4add(float4 a, float4 b) {
  return make_float4(a.x + b.x, a.y + b.y, a.z + b.z, a.w + b.w);
}

// ---------------- matvec to K-split partials; optional LN-from-stats prologue ----------------
struct MvP {
  const float* W0; const float* W1; const float* W2;
  float* pout;
  const float* hsrc;    // mode 0: precomputed h [8][K]
  const float* xsrc;    // mode 1: raw vector [8][K]
  const float* stats;   // mode 1: [8][nchunk][2] (sum, sumsq)
  const float* bias;    // mode 1: width-K bias added after LN
  int K, N, NPAD, CB, KS, mode, nchunk;
};

template <int C>
__global__ __launch_bounds__(256) void mv_k(MvP p) {
  __shared__ float h[8 * 128];
  __shared__ float mrs[8][2];
  const int tid = threadIdx.x;
  const int per = p.CB * p.KS;
  const int m = blockIdx.x / per, rem = blockIdx.x % per;
  const int ks = rem / p.CB, cb = rem % p.CB;
  const int BK = p.K / p.KS;
  const int k0 = ks * BK;
  const int n0 = cb * 256 * C;
  const int bk4 = BK >> 2;

  if (p.mode == 1) {
    if (tid < 8) {
      float s = 0.f, ss = 0.f;
      for (int c = 0; c < p.nchunk; ++c) {
        s += p.stats[(tid * p.nchunk + c) * 2];
        ss += p.stats[(tid * p.nchunk + c) * 2 + 1];
      }
      float mean = s / p.K;
      mrs[tid][0] = mean;
      mrs[tid][1] = rsqrtf(ss / p.K - mean * mean + EPSF);
    }
    __syncthreads();
    for (int i = tid; i < 8 * bk4; i += 256) {
      int r = i / bk4, q = i - r * bk4;
      float4 xv = *reinterpret_cast<const float4*>(p.xsrc + (size_t)r * p.K + k0 + q * 4);
      float4 bi = *reinterpret_cast<const float4*>(p.bias + k0 + q * 4);
      float mm = mrs[r][0], rs = mrs[r][1];
      float4 o = make_float4((xv.x - mm) * rs + bi.x, (xv.y - mm) * rs + bi.y,
                             (xv.z - mm) * rs + bi.z, (xv.w - mm) * rs + bi.w);
      *reinterpret_cast<float4*>(h + r * BK + q * 4) = o;
    }
  } else {
    for (int i = tid; i < 8 * bk4; i += 256) {
      int r = i / bk4, q = i - r * bk4;
      *reinterpret_cast<float4*>(h + r * BK + q * 4) =
          *reinterpret_cast<const float4*>(p.hsrc + (size_t)r * p.K + k0 + q * 4);
    }
  }
  __syncthreads();

  const float* W = (m == 0) ? p.W0 : (m == 1) ? p.W1 : p.W2;
  float* pr = p.pout + (size_t)(m * p.KS + ks) * 8 * p.NPAD;

  if (C == 1) {
    int col = n0 + tid;
    if (col >= p.N) return;
    const float* wp = W + (size_t)k0 * p.N + col;
    float acc[8] = {0.f, 0.f, 0.f, 0.f, 0.f, 0.f, 0.f, 0.f};
    for (int kk = 0; kk < BK; kk += 8) {
      float w[8];
#pragma unroll
      for (int j = 0; j < 8; ++j) w[j] = wp[(size_t)(kk + j) * p.N];
#pragma unroll
      for (int j = 0; j < 8; ++j) {
#pragma unroll
        for (int r = 0; r < 8; ++r) acc[r] += h[r * BK + kk + j] * w[j];
      }
    }
#pragma unroll
    for (int r = 0; r < 8; ++r) pr[(size_t)r * p.NPAD + col] = acc[r];
  } else {
    int nb = n0 + tid * 4;
    if (nb >= p.N) return;
    const float* wp = W + (size_t)k0 * p.N + nb;
    if (nb + 3 < p.N) {
      float4 acc[8];
#pragma unroll
      for (int r = 0; r < 8; ++r) acc[r] = make_float4(0.f, 0.f, 0.f, 0.f);
      for (int kk = 0; kk < BK; kk += 8) {
        float4 w[8];
#pragma unroll
        for (int j = 0; j < 8; ++j)
          w[j] = *reinterpret_cast<const float4*>(wp + (size_t)(kk + j) * p.N);
#pragma unroll
        for (int j = 0; j < 8; ++j) {
#pragma unroll
          for (int r = 0; r < 8; ++r) {
            float hv = h[r * BK + kk + j];
            acc[r].x += hv * w[j].x; acc[r].y += hv * w[j].y;
            acc[r].z += hv * w[j].z; acc[r].w += hv * w[j].w;
          }
        }
      }
#pragma unroll
      for (int r = 0; r < 8; ++r)
        *reinterpret_cast<float4*>(pr + (size_t)r * p.NPAD + nb) = acc[r];
    } else {
      for (int c = 0; c < 4; ++c) {
        if (nb + c >= p.N) break;
        float acc[8] = {0.f, 0.f, 0.f, 0.f, 0.f, 0.f, 0.f, 0.f};
        for (int kk = 0; kk < BK; ++kk) {
          float w = wp[(size_t)kk * p.N + c];
#pragma unroll
          for (int r = 0; r < 8; ++r) acc[r] += h[r * BK + kk] * w;
        }
#pragma unroll
        for (int r = 0; r < 8; ++r) pr[(size_t)r * p.NPAD + nb + c] = acc[r];
      }
    }
  }
}

// ---------------- combine fc01 partials -> g = gelu(A)*B + chunk stats ----------------
__global__ __launch_bounds__(256) void combine_g(const float* __restrict__ P,
    float* __restrict__ g, float* __restrict__ gstats) {
  __shared__ float tmp[8];
  int b = blockIdx.x >> 3, ch = blockIdx.x & 7;
  int tid = threadIdx.x;
  int col = ch * 512 + tid * 2;
  const float* baseA = P + (size_t)b * NG + col;
  const float* baseB = P + ((size_t)8 * 8 + b) * NG + col;
  float2 a = make_float2(0.f, 0.f), bb = make_float2(0.f, 0.f);
#pragma unroll
  for (int ks = 0; ks < 8; ++ks) {
    float2 pa = *reinterpret_cast<const float2*>(baseA + (size_t)ks * 8 * NG);
    float2 pb = *reinterpret_cast<const float2*>(baseB + (size_t)ks * 8 * NG);
    a.x += pa.x; a.y += pa.y; bb.x += pb.x; bb.y += pb.y;
  }
  float2 gg;
  gg.x = 0.5f * a.x * (1.f + erff(a.x * 0.70710678118f)) * bb.x;
  gg.y = 0.5f * a.y * (1.f + erff(a.y * 0.70710678118f)) * bb.y;
  *reinterpret_cast<float2*>(g + (size_t)b * NG + col) = gg;
  float s = gg.x + gg.y, ss = gg.x * gg.x + gg.y * gg.y;
  block_red2(s, ss, tmp);
  if (tid == 0) {
    gstats[(b * 8 + ch) * 2] = s;
    gstats[(b * 8 + ch) * 2 + 1] = ss;
  }
}

// ---------------- combine fc2 partials + resid -> x_next + chunk stats ----------------
__global__ __launch_bounds__(256) void combine_x(const float* __restrict__ P,
    const float* __restrict__ resid, float* __restrict__ xout, float* __restrict__ xstats) {
  __shared__ float tmp[8];
  int b = blockIdx.x >> 2, ch = blockIdx.x & 3;
  int tid = threadIdx.x;
  int col = ch * 256 + tid;
  float acc = resid[(size_t)b * NE + col];
  const float* base = P + (size_t)b * NE + col;
#pragma unroll
  for (int ks = 0; ks < 32; ++ks) acc += base[(size_t)ks * 8 * NE];
  xout[(size_t)b * NE + col] = acc;
  float s = acc, ss = acc * acc;
  block_red2(s, ss, tmp);
  if (tid == 0) {
    xstats[(b * 4 + ch) * 2] = s;
    xstats[(b * 4 + ch) * 2 + 1] = ss;
  }
}

// ---------------- embed (blocks 0-7) + mask-detect (block 8) + ast copy ----------------
__global__ __launch_bounds__(256) void embed_copy(const float* __restrict__ tok,
    const float* __restrict__ pos, const int* __restrict__ prev, const int* __restrict__ tixp,
    const float* __restrict__ lnb, const float* __restrict__ lns,
    const void* __restrict__ maskp, float* __restrict__ x0, float* __restrict__ xstats,
    unsigned* __restrict__ mflag, const float4* __restrict__ astv, float4* __restrict__ oastv) {
  __shared__ float tmp[8];
  int bid = blockIdx.x, tid = threadIdx.x;
  if (bid < 8) {
    int b = bid;
    const float* te = tok + (size_t)prev[0] * NE;
    const float* pe = pos + (size_t)tixp[0] * NE;
    float4 t4 = *reinterpret_cast<const float4*>(te + tid * 4);
    float4 p4 = *reinterpret_cast<const float4*>(pe + tid * 4);
    float4 v = make_float4(t4.x + p4.x, t4.y + p4.y, t4.z + p4.z, t4.w + p4.w);
    float s = v.x + v.y + v.z + v.w;
    float ss = v.x * v.x + v.y * v.y + v.z * v.z + v.w * v.w;
    block_red2(s, ss, tmp);
    float m = s / NE, rs = rsqrtf(ss / NE - m * m + EPSF);
    float4 sc = *reinterpret_cast<const float4*>(lns + tid * 4);
    float4 bi = *reinterpret_cast<const float4*>(lnb + tid * 4);
    float4 x;
    x.x = (v.x - m) * rs * sc.x + bi.x; x.y = (v.y - m) * rs * sc.y + bi.y;
    x.z = (v.z - m) * rs * sc.z + bi.z; x.w = (v.w - m) * rs * sc.w + bi.w;
    *reinterpret_cast<float4*>(x0 + (size_t)b * NE + tid * 4) = x;
    float s2 = x.x + x.y + x.z + x.w;
    float ss2 = x.x * x.x + x.y * x.y + x.z * x.z + x.w * x.w;
    block_red2(s2, ss2, tmp);
    if (tid == 0) {
      xstats[(b * 4 + 0) * 2] = s2; xstats[(b * 4 + 0) * 2 + 1] = ss2;
#pragma unroll
      for (int c = 1; c < 4; ++c) { xstats[(b * 4 + c) * 2] = 0.f; xstats[(b * 4 + c) * 2 + 1] = 0.f; }
    }
    return;
  }
  if (bid == 8) {
    __shared__ int f;
    if (tid == 0) f = 1;
    __syncthreads();
    if (tid < 128) { if (((const unsigned*)maskp)[tid] > 1u) f = 0; }
    __syncthreads();
    if (tid == 0) *mflag = f ? 1u : 2u;
  }
  const int n4 = NL * 16 * NIMG * (NE / 4);
  for (int i = (bid - 8) * 256 + tid; i < n4; i += 4096 * 256) oastv[i] = astv[i];
}

// ---------------- x2 = x + LN(sum part; lns1,lnb1); h = LN(x2)+lnb2 ----------------
__global__ __launch_bounds__(256) void ln_res_sum(const float* __restrict__ xres,
    const float* __restrict__ part, const float* __restrict__ lns1,
    const float* __restrict__ lnb1, const float* __restrict__ lnb2,
    float* __restrict__ xstore, float* __restrict__ hout) {
  __shared__ float tmp[8];
  int b = blockIdx.x, tid = threadIdx.x;
  int col = tid * 4;
  float4 sv = make_float4(0.f, 0.f, 0.f, 0.f);
  const float* base = part + (size_t)b * 1024 + col;
#pragma unroll
  for (int h = 0; h < 16; h += 8) {
    float4 w[8];
#pragma unroll
    for (int j = 0; j < 8; ++j)
      w[j] = *reinterpret_cast<const float4*>(base + (size_t)(h + j) * 8192);
#pragma unroll
    for (int j = 0; j < 8; ++j) sv = f4add(sv, w[j]);
  }
  float s = sv.x + sv.y + sv.z + sv.w;
  float ss = sv.x * sv.x + sv.y * sv.y + sv.z * sv.z + sv.w * sv.w;
  block_red2(s, ss, tmp);
  float m1 = s / NE, rs1 = rsqrtf(ss / NE - m1 * m1 + EPSF);
  float4 xv = *reinterpret_cast<const float4*>(xres + (size_t)b * NE + col);
  float4 sc1 = *reinterpret_cast<const float4*>(lns1 + col);
  float4 b1 = *reinterpret_cast<const float4*>(lnb1 + col);
  float4 v;
  v.x = xv.x + (sv.x - m1) * rs1 * sc1.x + b1.x;
  v.y = xv.y + (sv.y - m1) * rs1 * sc1.y + b1.y;
  v.z = xv.z + (sv.z - m1) * rs1 * sc1.z + b1.z;
  v.w = xv.w + (sv.w - m1) * rs1 * sc1.w + b1.w;
  *reinterpret_cast<float4*>(xstore + (size_t)b * NE + col) = v;
  float s2 = v.x + v.y + v.z + v.w;
  float ss2 = v.x * v.x + v.y * v.y + v.z * v.z + v.w * v.w;
  block_red2(s2, ss2, tmp);
  float m2 = s2 / NE, rs2 = rsqrtf(ss2 / NE - m2 * m2 + EPSF);
  float4 b2 = *reinterpret_cast<const float4*>(lnb2 + col);
  float4 o;
  o.x = (v.x - m2) * rs2 + b2.x; o.y = (v.y - m2) * rs2 + b2.y;
  o.z = (v.z - m2) * rs2 + b2.z; o.w = (v.w - m2) * rs2 + b2.w;
  *reinterpret_cast<float4*>(hout + (size_t)b * NE + col) = o;
}

// ---------------- fused: qkv-reduce + fresh KV out + self-attn + @Wso ----------------
__global__ __launch_bounds__(256) void attn_fused(const float* __restrict__ Pqkv,
    const float* __restrict__ ast_l, const int* __restrict__ tixp,
    const float* __restrict__ Wso, float* __restrict__ spart, float* __restrict__ oast_l) {
  int b = blockIdx.x >> 4, hh = blockIdx.x & 15;
  int tid = threadIdx.x;
  int tix0 = tixp[0];
  int tixc = tix0 < 0 ? 0 : (tix0 > 255 ? 255 : tix0);
  int T = tixc + 1;
  __shared__ float qv[64];
  __shared__ float kf[64];
  __shared__ float vf[64];
  __shared__ float scb[256];
  __shared__ float red[256];
  __shared__ float pv[1024];
  __shared__ float ov[64];
  if (tid < 192) {
    int m = tid >> 6, d = tid & 63;
    const float* bp = Pqkv + (size_t)(m * 16) * 8192 + (size_t)b * 1024 + hh * 64 + d;
    float acc = 0.f;
#pragma unroll
    for (int ks = 0; ks < 16; ++ks) acc += bp[(size_t)ks * 8192];
    if (m == 2) qv[d] = acc * 0.125f;
    else {
      if (m == 0) kf[d] = acc; else vf[d] = acc;
      if (tix0 >= 0 && tix0 < NIMG) {
        int row = (m == 0) ? b : 8 + b;
        oast_l[((size_t)row * NIMG + tix0) * NE + hh * 64 + d] = acc;
      }
    }
  }
  __syncthreads();
  float sj = -INFINITY;
  if (tid < T) {
    const float* kr = (tid == tixc) ? kf : (ast_l + ((size_t)b * NIMG + tid) * NE + hh * 64);
    float s = 0.f;
#pragma unroll
    for (int d0 = 0; d0 < 64; d0 += 4) {
      float4 k4 = *reinterpret_cast<const float4*>(kr + d0);
      s += qv[d0] * k4.x + qv[d0 + 1] * k4.y + qv[d0 + 2] * k4.z + qv[d0 + 3] * k4.w;
    }
    sj = s;
  }
  red[tid] = sj; __syncthreads();
  for (int o = 128; o; o >>= 1) { if (tid < o) red[tid] = fmaxf(red[tid], red[tid + o]); __syncthreads(); }
  float mx = red[0]; __syncthreads();
  float e = (tid < T) ? __expf(sj - mx) : 0.f;
  red[tid] = e; __syncthreads();
  for (int o = 128; o; o >>= 1) { if (tid < o) red[tid] += red[tid + o]; __syncthreads(); }
  float inv = 1.f / red[0];
  scb[tid] = e * inv;
  __syncthreads();
  {
    int c = tid >> 4, d4 = (tid & 15) * 4;
    float4 a = make_float4(0.f, 0.f, 0.f, 0.f);
    for (int j = c; j < T; j += 16) {
      const float* vr = (j == tixc) ? vf : (ast_l + ((size_t)(8 + b) * NIMG + j) * NE + hh * 64);
      float4 v4 = *reinterpret_cast<const float4*>(vr + d4);
      float w = scb[j];
      a.x += w * v4.x; a.y += w * v4.y; a.z += w * v4.z; a.w += w * v4.w;
    }
    pv[c * 64 + d4 + 0] = a.x; pv[c * 64 + d4 + 1] = a.y;
    pv[c * 64 + d4 + 2] = a.z; pv[c * 64 + d4 + 3] = a.w;
  }
  __syncthreads();
  if (tid < 64) {
    float s = 0.f;
#pragma unroll
    for (int c = 0; c < 16; ++c) s += pv[c * 64 + tid];
    ov[tid] = s;
  }
  __syncthreads();
  {
    int nb = tid * 4;
    const float* wp = Wso + (size_t)(hh * 64) * NE + nb;
    float4 acc = make_float4(0.f, 0.f, 0.f, 0.f);
    for (int d = 0; d < 64; d += 8) {
      float4 w[8];
#pragma unroll
      for (int j = 0; j < 8; ++j)
        w[j] = *reinterpret_cast<const float4*>(wp + (size_t)(d + j) * NE);
#pragma unroll
      for (int j = 0; j < 8; ++j) {
        float o = ov[d + j];
        acc.x += o * w[j].x; acc.y += o * w[j].y; acc.z += o * w[j].z; acc.w += o * w[j].w;
      }
    }
    *reinterpret_cast<float4*>(spart + ((size_t)hh * 8 + b) * 1024 + nb) = acc;
  }
}

// ---------------- fused: x2/h2 LN + cross attention chain ----------------
__global__ __launch_bounds__(256) void cross_fused(const float* __restrict__ xres,
    const float* __restrict__ sspart, const float* __restrict__ sls,
    const float* __restrict__ slb, const float* __restrict__ peb,
    const float* __restrict__ Weq, const float* __restrict__ Wek,
    const float* __restrict__ Wev, const float* __restrict__ Weo,
    const float* __restrict__ X, const void* __restrict__ maskp,
    const unsigned* __restrict__ mflag, float* __restrict__ x2store,
    float* __restrict__ spart) {
  int b = blockIdx.x >> 4, hh = blockIdx.x & 15;
  int tid = threadIdx.x;
  __shared__ float vecA[NE];
  __shared__ float vecB[NE];
  __shared__ float red[256];
  __shared__ float w_[NTT];
  __shared__ float qv[64];
  __shared__ float oe[64];
  __shared__ float tmp[8];
  int mi32 = (*mflag == 1u);
  {
    int col = tid * 4;
    float4 sv = make_float4(0.f, 0.f, 0.f, 0.f);
    const float* base = sspart + (size_t)b * 1024 + col;
#pragma unroll
    for (int h = 0; h < 16; h += 8) {
      float4 w[8];
#pragma unroll
      for (int j = 0; j < 8; ++j)
        w[j] = *reinterpret_cast<const float4*>(base + (size_t)(h + j) * 8192);
#pragma unroll
      for (int j = 0; j < 8; ++j) sv = f4add(sv, w[j]);
    }
    float s = sv.x + sv.y + sv.z + sv.w;
    float ss = sv.x * sv.x + sv.y * sv.y + sv.z * sv.z + sv.w * sv.w;
    block_red2(s, ss, tmp);
    float m1 = s / NE, rs1 = rsqrtf(ss / NE - m1 * m1 + EPSF);
    float4 xv = *reinterpret_cast<const float4*>(xres + (size_t)b * NE + col);
    float4 sc1 = *reinterpret_cast<const float4*>(sls + col);
    float4 b1 = *reinterpret_cast<const float4*>(slb + col);
    float4 v;
    v.x = xv.x + (sv.x - m1) * rs1 * sc1.x + b1.x;
    v.y = xv.y + (sv.y - m1) * rs1 * sc1.y + b1.y;
    v.z = xv.z + (sv.z - m1) * rs1 * sc1.z + b1.z;
    v.w = xv.w + (sv.w - m1) * rs1 * sc1.w + b1.w;
    if (hh == 0)
      *reinterpret_cast<float4*>(x2store + (size_t)b * NE + col) = v;
    float s2 = v.x + v.y + v.z + v.w;
    float ss2 = v.x * v.x + v.y * v.y + v.z * v.z + v.w * v.w;
    block_red2(s2, ss2, tmp);
    float m2 = s2 / NE, rs2 = rsqrtf(ss2 / NE - m2 * m2 + EPSF);
    float4 b2 = *reinterpret_cast<const float4*>(peb + col);
    float4 o;
    o.x = (v.x - m2) * rs2 + b2.x; o.y = (v.y - m2) * rs2 + b2.y;
    o.z = (v.z - m2) * rs2 + b2.z; o.w = (v.w - m2) * rs2 + b2.w;
    reinterpret_cast<float4*>(vecA)[tid] = o;
  }
  __syncthreads();

  {
    int d4 = (tid & 15) * 4, ech = tid >> 4;
    const float* base = Weq + hh * 64 + d4;
    float4 a = make_float4(0.f, 0.f, 0.f, 0.f);
    for (int e = ech * 64; e < ech * 64 + 64; e += 8) {
      float4 w[8];
#pragma unroll
      for (int j = 0; j < 8; ++j)
        w[j] = *reinterpret_cast<const float4*>(base + (size_t)(e + j) * NE);
#pragma unroll
      for (int j = 0; j < 8; ++j) {
        float hv = vecA[e + j];
        a.x += hv * w[j].x; a.y += hv * w[j].y; a.z += hv * w[j].z; a.w += hv * w[j].w;
      }
    }
    vecB[ech * 64 + d4 + 0] = a.x; vecB[ech * 64 + d4 + 1] = a.y;
    vecB[ech * 64 + d4 + 2] = a.z; vecB[ech * 64 + d4 + 3] = a.w;
  }
  __syncthreads();
  if (tid < 64) {
    float s = 0.f;
#pragma unroll
    for (int c = 0; c < 16; ++c) s += vecB[c * 64 + tid];
    qv[tid] = s;
  }
  __syncthreads();

  {
    float qwtmp[4];
#pragma unroll
    for (int jj = 0; jj < 4; ++jj) {
      int e = tid + 256 * jj;
      const float* wr = Wek + (size_t)e * NE + hh * 64;
      float a = 0.f;
#pragma unroll
      for (int d0 = 0; d0 < 64; d0 += 4) {
        float4 w4 = *reinterpret_cast<const float4*>(wr + d0);
        a += qv[d0] * w4.x + qv[d0 + 1] * w4.y + qv[d0 + 2] * w4.z + qv[d0 + 3] * w4.w;
      }
      qwtmp[jj] = a;
    }
#pragma unroll
    for (int jj = 0; jj < 4; ++jj) vecB[tid + 256 * jj] = qwtmp[jj];
  }
  __syncthreads();

  {
    int t = tid & 63, ec = tid >> 6;
    const float* xr = X + ((size_t)b * NTT + t) * NE + ec * 256;
    float part = 0.f;
#pragma unroll 4
    for (int i = 0; i < 256; i += 4) {
      float4 x4 = *reinterpret_cast<const float4*>(xr + i);
      part += vecB[ec * 256 + i] * x4.x + vecB[ec * 256 + i + 1] * x4.y +
              vecB[ec * 256 + i + 2] * x4.z + vecB[ec * 256 + i + 3] * x4.w;
    }
    red[ec * 64 + t] = part;
  }
  __syncthreads();
  float sco = -INFINITY;
  if (tid < 64) {
    float s = (red[tid] + red[64 + tid] + red[128 + tid] + red[192 + tid]) * 0.125f;
    int idx = b * NTT + tid;
    bool valid = mi32 ? (((const int*)maskp)[idx] != 0)
                      : (((const unsigned char*)maskp)[idx] != 0);
    sco = valid ? s : -INFINITY;
  }
  __syncthreads();
  red[tid] = (tid < 64) ? sco : -INFINITY; __syncthreads();
  for (int o = 128; o; o >>= 1) { if (tid < o) red[tid] = fmaxf(red[tid], red[tid + o]); __syncthreads(); }
  float mx = red[0]; __syncthreads();
  float e = (tid < 64) ? __expf(sco - mx) : 0.f;
  red[tid] = e; __syncthreads();
  for (int o = 128; o; o >>= 1) { if (tid < o) red[tid] += red[tid + o]; __syncthreads(); }
  if (tid < 64) w_[tid] = e / red[0];
  __syncthreads();

  {
    float4 a = make_float4(0.f, 0.f, 0.f, 0.f);
    const float* xb = X + (size_t)b * NTT * NE + tid * 4;
    for (int t = 0; t < NTT; t += 4) {
#pragma unroll
      for (int j = 0; j < 4; ++j) {
        float4 x4 = *reinterpret_cast<const float4*>(xb + (size_t)(t + j) * NE);
        float w = w_[t + j];
        a.x += w * x4.x; a.y += w * x4.y; a.z += w * x4.z; a.w += w * x4.w;
      }
    }
    reinterpret_cast<float4*>(vecA)[tid] = a;
  }
  __syncthreads();

  {
    int d4 = (tid & 15) * 4, ech = tid >> 4;
    const float* base = Wev + hh * 64 + d4;
    float4 a = make_float4(0.f, 0.f, 0.f, 0.f);
    for (int e = ech * 64; e < ech * 64 + 64; e += 8) {
      float4 w[8];
#pragma unroll
      for (int j = 0; j < 8; ++j)
        w[j] = *reinterpret_cast<const float4*>(base + (size_t)(e + j) * NE);
#pragma unroll
      for (int j = 0; j < 8; ++j) {
        float hv = vecA[e + j];
        a.x += hv * w[j].x; a.y += hv * w[j].y; a.z += hv * w[j].z; a.w += hv * w[j].w;
      }
    }
    vecB[ech * 64 + d4 + 0] = a.x; vecB[ech * 64 + d4 + 1] = a.y;
    vecB[ech * 64 + d4 + 2] = a.z; vecB[ech * 64 + d4 + 3] = a.w;
  }
  __syncthreads();
  if (tid < 64) {
    float s = 0.f;
#pragma unroll
    for (int c = 0; c < 16; ++c) s += vecB[c * 64 + tid];
    oe[tid] = s;
  }
  __syncthreads();

  {
    int nb = tid * 4;
    const float* wp = Weo + (size_t)(hh * 64) * NE + nb;
    float4 acc = make_float4(0.f, 0.f, 0.f, 0.f);
    for (int d = 0; d < 64; d += 8) {
      float4 w[8];
#pragma unroll
      for (int j = 0; j < 8; ++j)
        w[j] = *reinterpret_cast<const float4*>(wp + (size_t)(d + j) * NE);
#pragma unroll
      for (int j = 0; j < 8; ++j) {
        float o = oe[d + j];
        acc.x += o * w[j].x; acc.y += o * w[j].y; acc.z += o * w[j].z; acc.w += o * w[j].w;
      }
    }
    *reinterpret_cast<float4*>(spart + ((size_t)hh * 8 + b) * 1024 + nb) = acc;
  }
}

// ---------------- reduce lm_head partials -> logits ----------------
__global__ __launch_bounds__(256) void reduce_logits(const float* __restrict__ P,
                                                     float* __restrict__ logits) {
  int r = blockIdx.x / 17, cc = blockIdx.x % 17;
  int col = cc * 1024 + threadIdx.x * 4;
  if (col >= NV) return;
  if (col + 3 < NV) {
    const float* base = P + (size_t)r * NVPAD + col;
    float4 acc = make_float4(0.f, 0.f, 0.f, 0.f);
    for (int ks = 0; ks < 16; ks += 8) {
      float4 w[8];
#pragma unroll
      for (int j = 0; j < 8; ++j)
        w[j] = *reinterpret_cast<const float4*>(base + (size_t)(ks + j) * 8 * NVPAD);
#pragma unroll
      for (int j = 0; j < 8; ++j) acc = f4add(acc, w[j]);
    }
    *reinterpret_cast<float4*>(logits + (size_t)r * NV + col) = acc;
  } else {
    for (int c = 0; c < 4 && col + c < NV; ++c) {
      float a = 0.f;
      for (int ks = 0; ks < 16; ++ks) a += P[((size_t)ks * 8 + r) * NVPAD + col + c];
      logits[(size_t)r * NV + col + c] = a;
    }
  }
}

extern "C" void kernel_launch(void* const* d_in, const int* in_sizes, int n_in,
                              void* d_out, int out_size, void* d_ws, size_t ws_size,
                              hipStream_t stream) {
  const float* enc_state = (const float*)d_in[0];
  const float* ast_in    = (const float*)d_in[1];
  const void* amask      = d_in[2];
  const int* prev = (const int*)d_in[3];
  const int* tix  = (const int*)d_in[4];
  const float* embed_tok = (const float*)d_in[5];
  const float* embed_pos = (const float*)d_in[6];
  const float* lnemb_s = (const float*)d_in[7];
  const float* lnemb_b = (const float*)d_in[8];
  const float* psb = (const float*)d_in[9];
  const float* Wsq = (const float*)d_in[10];
  const float* Wsk = (const float*)d_in[11];
  const float* Wsv = (const float*)d_in[12];
  const float* Wso = (const float*)d_in[13];
  const float* sls = (const float*)d_in[14];
  const float* slb = (const float*)d_in[15];
  const float* peb = (const float*)d_in[16];
  const float* Weq = (const float*)d_in[17];
  const float* Wek = (const float*)d_in[18];
  const float* Wev = (const float*)d_in[19];
  const float* Weo = (const float*)d_in[20];
  const float* els = (const float*)d_in[21];
  const float* elb = (const float*)d_in[22];
  const float* g0b = (const float*)d_in[23];
  const float* Wf0 = (const float*)d_in[24];
  const float* Wf1 = (const float*)d_in[25];
  const float* g1b = (const float*)d_in[26];
  const float* Wf2 = (const float*)d_in[27];
  const float* flb = (const float*)d_in[28];
  const float* Wlm = (const float*)d_in[29];

  float* ws = (float*)d_ws;
  float* logits = (float*)d_out;
  float* out_ast = logits + (size_t)NB * NV;

  embed_copy<<<4104, 256, 0, stream>>>(embed_tok, embed_pos, prev, tix, lnemb_b, lnemb_s,
                                       amask, ws + XBUF, ws + XSTAT,
                                       (unsigned*)(ws + MFLAG),
                                       (const float4*)ast_in, (float4*)out_ast);

  for (int l = 0; l < NL; ++l) {
    size_t wE = (size_t)l * NE * NE;
    size_t wG = (size_t)l * NE * NG;

    {  // qkv partials: C=1, CB=4, KS=16, LN-from-stats prologue
      MvP p{}; p.W0 = Wsk + wE; p.W1 = Wsv + wE; p.W2 = Wsq + wE;
      p.pout = ws + P_QKV; p.xsrc = ws + XBUF; p.stats = ws + XSTAT;
      p.bias = psb + (size_t)l * NE;
      p.K = NE; p.N = NE; p.NPAD = NE; p.CB = 4; p.KS = 16; p.mode = 1; p.nchunk = 4;
      mv_k<1><<<3 * 4 * 16, 256, 0, stream>>>(p);
    }
    attn_fused<<<NB * NH, 256, 0, stream>>>(ws + P_QKV,
                                            ast_in + (size_t)l * 16 * NIMG * NE, tix,
                                            Wso + wE, ws + SSPART,
                                            out_ast + (size_t)l * 16 * NIMG * NE);
    cross_fused<<<NB * NH, 256, 0, stream>>>(ws + XBUF, ws + SSPART,
                                             sls + (size_t)l * NE, slb + (size_t)l * NE,
                                             peb + (size_t)l * NE,
                                             Weq + wE, Wek + wE, Wev + wE, Weo + wE,
                                             enc_state, amask,
                                             (const unsigned*)(ws + MFLAG),
                                             ws + DX2, ws + SEPART);
    ln_res_sum<<<NB, 256, 0, stream>>>(ws + DX2, ws + SEPART, els + (size_t)l * NE,
                                       elb + (size_t)l * NE, g0b + (size_t)l * NE,
                                       ws + DX3, ws + DH3);
    {  // fc0/fc1 partials: C=1, CB=16, KS=8, precomputed h3
      MvP p{}; p.W0 = Wf0 + wG; p.W1 = Wf1 + wG;
      p.pout = ws + P_FC01; p.hsrc = ws + DH3;
      p.K = NE; p.N = NG; p.NPAD = NG; p.CB = 16; p.KS = 8; p.mode = 0;
      mv_k<1><<<2 * 16 * 8, 256, 0, stream>>>(p);
    }
    combine_g<<<64, 256, 0, stream>>>(ws + P_FC01, ws + DG, ws + GSTAT);
    {  // fc2 partials: C=1, CB=4, KS=32, LN(g)-from-stats prologue
      MvP p{}; p.W0 = Wf2 + (size_t)l * NG * NE;
      p.pout = ws + P_FC2; p.xsrc = ws + DG; p.stats = ws + GSTAT;
      p.bias = g1b + (size_t)l * NG;
      p.K = NG; p.N = NE; p.NPAD = NE; p.CB = 4; p.KS = 32; p.mode = 1; p.nchunk = 8;
      mv_k<1><<<4 * 32, 256, 0, stream>>>(p);
    }
    combine_x<<<32, 256, 0, stream>>>(ws + P_FC2, ws + DX3, ws + XBUF, ws + XSTAT);
  }
  {  // lm_head partials: C=4, CB=17, KS=16, LN(x4)-from-stats prologue
    MvP p{}; p.W0 = Wlm;
    p.pout = ws + P_LM; p.xsrc = ws + XBUF; p.stats = ws + XSTAT; p.bias = flb;
    p.K = NE; p.N = NV; p.NPAD = NVPAD; p.CB = 17; p.KS = 16; p.mode = 1; p.nchunk = 4;
    mv_k<4><<<17 * 16, 256, 0, stream>>>(p);
  }
  reduce_logits<<<NB * 17, 256, 0, stream>>>(ws + P_LM, logits);
}

// Round 12
// 478.784 us; speedup vs baseline: 8.1817x; 1.0036x over previous
//
#include <hip/hip_runtime.h>
#include <math.h>

#define EPSF 1e-6f

#define NL 4
#define NB 8
#define NE 1024
#define NH 16
#define NG 4096
#define NIMG 256
#define NTT 64
#define NV 16385
#define NVPAD 17408

// ---- workspace float offsets ----
#define P_QKV   0          // [3][16][8][1024]
#define P_FC01  393216     // [2][8][8][4096]
#define P_FC2   917504     // [32][8][1024]
#define P_LM    1179648    // [16][8][17408]
#define SSPART  3407872    // [16][8][1024]
#define SEPART  3538944    // [16][8][1024]
#define XBUF    3670016    // [8][1024]
#define DX2     3678208
#define DX3     3686400
#define DH3     3694592
#define DG      3702784    // [8][4096]
#define XSTAT   3735552    // [8][4][2]
#define GSTAT   3735616    // [8][8][2]
#define MFLAG   3735744

__device__ inline void wave_red2(float& a, float& b) {
#pragma unroll
  for (int o = 32; o; o >>= 1) { a += __shfl_xor(a, o); b += __shfl_xor(b, o); }
}

__device__ inline void block_red2(float& s, float& ss, float* tmp) {
  wave_red2(s, ss);
  int wv = threadIdx.x >> 6, ln = threadIdx.x & 63;
  if (ln == 0) { tmp[wv] = s; tmp[4 + wv] = ss; }
  __syncthreads();
  s = tmp[0] + tmp[1] + tmp[2] + tmp[3];
  ss = tmp[4] + tmp[5] + tmp[6] + tmp[7];
  __syncthreads();
}

__device__ inline float4 f4add(float4 a, float4 b) {
  return make_float4(a.x + b.x, a.y + b.y, a.z + b.z, a.w + b.w);
}

// ---------------- matvec to K-split partials; optional LN-from-stats prologue ----------------
struct MvP {
  const float* W0; const float* W1; const float* W2;
  float* pout;
  const float* hsrc;    // mode 0: precomputed h [8][K]
  const float* xsrc;    // mode 1: raw vector [8][K]
  const float* stats;   // mode 1: [8][nchunk][2] (sum, sumsq)
  const float* bias;    // mode 1: width-K bias added after LN
  int K, N, NPAD, CB, KS, mode, nchunk;
};

template <int C>
__global__ __launch_bounds__(256) void mv_k(MvP p) {
  __shared__ float h[8 * 128];
  __shared__ float mrs[8][2];
  const int tid = threadIdx.x;
  const int per = p.CB * p.KS;
  const int m = blockIdx.x / per, rem = blockIdx.x % per;
  const int ks = rem / p.CB, cb = rem % p.CB;
  const int BK = p.K / p.KS;
  const int k0 = ks * BK;
  const int n0 = cb * 256 * C;
  const int bk4 = BK >> 2;

  if (p.mode == 1) {
    if (tid < 8) {
      float s = 0.f, ss = 0.f;
      for (int c = 0; c < p.nchunk; ++c) {
        s += p.stats[(tid * p.nchunk + c) * 2];
        ss += p.stats[(tid * p.nchunk + c) * 2 + 1];
      }
      float mean = s / p.K;
      mrs[tid][0] = mean;
      mrs[tid][1] = rsqrtf(ss / p.K - mean * mean + EPSF);
    }
    __syncthreads();
    for (int i = tid; i < 8 * bk4; i += 256) {
      int r = i / bk4, q = i - r * bk4;
      float4 xv = *reinterpret_cast<const float4*>(p.xsrc + (size_t)r * p.K + k0 + q * 4);
      float4 bi = *reinterpret_cast<const float4*>(p.bias + k0 + q * 4);
      float mm = mrs[r][0], rs = mrs[r][1];
      float4 o = make_float4((xv.x - mm) * rs + bi.x, (xv.y - mm) * rs + bi.y,
                             (xv.z - mm) * rs + bi.z, (xv.w - mm) * rs + bi.w);
      *reinterpret_cast<float4*>(h + r * BK + q * 4) = o;
    }
  } else {
    for (int i = tid; i < 8 * bk4; i += 256) {
      int r = i / bk4, q = i - r * bk4;
      *reinterpret_cast<float4*>(h + r * BK + q * 4) =
          *reinterpret_cast<const float4*>(p.hsrc + (size_t)r * p.K + k0 + q * 4);
    }
  }
  __syncthreads();

  const float* W = (m == 0) ? p.W0 : (m == 1) ? p.W1 : p.W2;
  float* pr = p.pout + (size_t)(m * p.KS + ks) * 8 * p.NPAD;

  if (C == 1) {
    int col = n0 + tid;
    if (col >= p.N) return;
    const float* wp = W + (size_t)k0 * p.N + col;
    float acc[8] = {0.f, 0.f, 0.f, 0.f, 0.f, 0.f, 0.f, 0.f};
    for (int kk = 0; kk < BK; kk += 8) {
      float w[8];
#pragma unroll
      for (int j = 0; j < 8; ++j) w[j] = wp[(size_t)(kk + j) * p.N];
#pragma unroll
      for (int j = 0; j < 8; ++j) {
#pragma unroll
        for (int r = 0; r < 8; ++r) acc[r] += h[r * BK + kk + j] * w[j];
      }
    }
#pragma unroll
    for (int r = 0; r < 8; ++r) pr[(size_t)r * p.NPAD + col] = acc[r];
  } else {
    int nb = n0 + tid * 4;
    if (nb >= p.N) return;
    const float* wp = W + (size_t)k0 * p.N + nb;
    if (nb + 3 < p.N) {
      float4 acc[8];
#pragma unroll
      for (int r = 0; r < 8; ++r) acc[r] = make_float4(0.f, 0.f, 0.f, 0.f);
      for (int kk = 0; kk < BK; kk += 8) {
        float4 w[8];
#pragma unroll
        for (int j = 0; j < 8; ++j)
          w[j] = *reinterpret_cast<const float4*>(wp + (size_t)(kk + j) * p.N);
#pragma unroll
        for (int j = 0; j < 8; ++j) {
#pragma unroll
          for (int r = 0; r < 8; ++r) {
            float hv = h[r * BK + kk + j];
            acc[r].x += hv * w[j].x; acc[r].y += hv * w[j].y;
            acc[r].z += hv * w[j].z; acc[r].w += hv * w[j].w;
          }
        }
      }
#pragma unroll
      for (int r = 0; r < 8; ++r)
        *reinterpret_cast<float4*>(pr + (size_t)r * p.NPAD + nb) = acc[r];
    } else {
      for (int c = 0; c < 4; ++c) {
        if (nb + c >= p.N) break;
        float acc[8] = {0.f, 0.f, 0.f, 0.f, 0.f, 0.f, 0.f, 0.f};
        for (int kk = 0; kk < BK; ++kk) {
          float w = wp[(size_t)kk * p.N + c];
#pragma unroll
          for (int r = 0; r < 8; ++r) acc[r] += h[r * BK + kk] * w;
        }
#pragma unroll
        for (int r = 0; r < 8; ++r) pr[(size_t)r * p.NPAD + nb + c] = acc[r];
      }
    }
  }
}

// ---------------- combine fc01 partials -> g = gelu(A)*B + chunk stats ----------------
__global__ __launch_bounds__(256) void combine_g(const float* __restrict__ P,
    float* __restrict__ g, float* __restrict__ gstats) {
  __shared__ float tmp[8];
  int b = blockIdx.x >> 3, ch = blockIdx.x & 7;
  int tid = threadIdx.x;
  int col = ch * 512 + tid * 2;
  const float* baseA = P + (size_t)b * NG + col;
  const float* baseB = P + ((size_t)8 * 8 + b) * NG + col;
  float2 a = make_float2(0.f, 0.f), bb = make_float2(0.f, 0.f);
#pragma unroll
  for (int ks = 0; ks < 8; ++ks) {
    float2 pa = *reinterpret_cast<const float2*>(baseA + (size_t)ks * 8 * NG);
    float2 pb = *reinterpret_cast<const float2*>(baseB + (size_t)ks * 8 * NG);
    a.x += pa.x; a.y += pa.y; bb.x += pb.x; bb.y += pb.y;
  }
  float2 gg;
  gg.x = 0.5f * a.x * (1.f + erff(a.x * 0.70710678118f)) * bb.x;
  gg.y = 0.5f * a.y * (1.f + erff(a.y * 0.70710678118f)) * bb.y;
  *reinterpret_cast<float2*>(g + (size_t)b * NG + col) = gg;
  float s = gg.x + gg.y, ss = gg.x * gg.x + gg.y * gg.y;
  block_red2(s, ss, tmp);
  if (tid == 0) {
    gstats[(b * 8 + ch) * 2] = s;
    gstats[(b * 8 + ch) * 2 + 1] = ss;
  }
}

// ---------------- combine fc2 partials + resid -> x_next + chunk stats ----------------
__global__ __launch_bounds__(256) void combine_x(const float* __restrict__ P,
    const float* __restrict__ resid, float* __restrict__ xout, float* __restrict__ xstats) {
  __shared__ float tmp[8];
  int b = blockIdx.x >> 2, ch = blockIdx.x & 3;
  int tid = threadIdx.x;
  int col = ch * 256 + tid;
  float acc = resid[(size_t)b * NE + col];
  const float* base = P + (size_t)b * NE + col;
#pragma unroll
  for (int ks = 0; ks < 32; ++ks) acc += base[(size_t)ks * 8 * NE];
  xout[(size_t)b * NE + col] = acc;
  float s = acc, ss = acc * acc;
  block_red2(s, ss, tmp);
  if (tid == 0) {
    xstats[(b * 4 + ch) * 2] = s;
    xstats[(b * 4 + ch) * 2 + 1] = ss;
  }
}

// ---------------- embed (blocks 0-7) + mask-detect (block 8) + ast copy ----------------
__global__ __launch_bounds__(256) void embed_copy(const float* __restrict__ tok,
    const float* __restrict__ pos, const int* __restrict__ prev, const int* __restrict__ tixp,
    const float* __restrict__ lnb, const float* __restrict__ lns,
    const void* __restrict__ maskp, float* __restrict__ x0, float* __restrict__ xstats,
    unsigned* __restrict__ mflag, const float4* __restrict__ astv, float4* __restrict__ oastv) {
  __shared__ float tmp[8];
  int bid = blockIdx.x, tid = threadIdx.x;
  if (bid < 8) {
    int b = bid;
    const float* te = tok + (size_t)prev[0] * NE;
    const float* pe = pos + (size_t)tixp[0] * NE;
    float4 t4 = *reinterpret_cast<const float4*>(te + tid * 4);
    float4 p4 = *reinterpret_cast<const float4*>(pe + tid * 4);
    float4 v = make_float4(t4.x + p4.x, t4.y + p4.y, t4.z + p4.z, t4.w + p4.w);
    float s = v.x + v.y + v.z + v.w;
    float ss = v.x * v.x + v.y * v.y + v.z * v.z + v.w * v.w;
    block_red2(s, ss, tmp);
    float m = s / NE, rs = rsqrtf(ss / NE - m * m + EPSF);
    float4 sc = *reinterpret_cast<const float4*>(lns + tid * 4);
    float4 bi = *reinterpret_cast<const float4*>(lnb + tid * 4);
    float4 x;
    x.x = (v.x - m) * rs * sc.x + bi.x; x.y = (v.y - m) * rs * sc.y + bi.y;
    x.z = (v.z - m) * rs * sc.z + bi.z; x.w = (v.w - m) * rs * sc.w + bi.w;
    *reinterpret_cast<float4*>(x0 + (size_t)b * NE + tid * 4) = x;
    float s2 = x.x + x.y + x.z + x.w;
    float ss2 = x.x * x.x + x.y * x.y + x.z * x.z + x.w * x.w;
    block_red2(s2, ss2, tmp);
    if (tid == 0) {
      xstats[(b * 4 + 0) * 2] = s2; xstats[(b * 4 + 0) * 2 + 1] = ss2;
#pragma unroll
      for (int c = 1; c < 4; ++c) { xstats[(b * 4 + c) * 2] = 0.f; xstats[(b * 4 + c) * 2 + 1] = 0.f; }
    }
    return;
  }
  if (bid == 8) {
    __shared__ int f;
    if (tid == 0) f = 1;
    __syncthreads();
    if (tid < 128) { if (((const unsigned*)maskp)[tid] > 1u) f = 0; }
    __syncthreads();
    if (tid == 0) *mflag = f ? 1u : 2u;
  }
  const int n4 = NL * 16 * NIMG * (NE / 4);
  for (int i = (bid - 8) * 256 + tid; i < n4; i += 4096 * 256) oastv[i] = astv[i];
}

// ---------------- x2 = x + LN(sum part; lns1,lnb1); h = LN(x2)+lnb2 ----------------
__global__ __launch_bounds__(256) void ln_res_sum(const float* __restrict__ xres,
    const float* __restrict__ part, const float* __restrict__ lns1,
    const float* __restrict__ lnb1, const float* __restrict__ lnb2,
    float* __restrict__ xstore, float* __restrict__ hout) {
  __shared__ float tmp[8];
  int b = blockIdx.x, tid = threadIdx.x;
  int col = tid * 4;
  float4 sv = make_float4(0.f, 0.f, 0.f, 0.f);
  const float* base = part + (size_t)b * 1024 + col;
#pragma unroll
  for (int h = 0; h < 16; h += 8) {
    float4 w[8];
#pragma unroll
    for (int j = 0; j < 8; ++j)
      w[j] = *reinterpret_cast<const float4*>(base + (size_t)(h + j) * 8192);
#pragma unroll
    for (int j = 0; j < 8; ++j) sv = f4add(sv, w[j]);
  }
  float s = sv.x + sv.y + sv.z + sv.w;
  float ss = sv.x * sv.x + sv.y * sv.y + sv.z * sv.z + sv.w * sv.w;
  block_red2(s, ss, tmp);
  float m1 = s / NE, rs1 = rsqrtf(ss / NE - m1 * m1 + EPSF);
  float4 xv = *reinterpret_cast<const float4*>(xres + (size_t)b * NE + col);
  float4 sc1 = *reinterpret_cast<const float4*>(lns1 + col);
  float4 b1 = *reinterpret_cast<const float4*>(lnb1 + col);
  float4 v;
  v.x = xv.x + (sv.x - m1) * rs1 * sc1.x + b1.x;
  v.y = xv.y + (sv.y - m1) * rs1 * sc1.y + b1.y;
  v.z = xv.z + (sv.z - m1) * rs1 * sc1.z + b1.z;
  v.w = xv.w + (sv.w - m1) * rs1 * sc1.w + b1.w;
  *reinterpret_cast<float4*>(xstore + (size_t)b * NE + col) = v;
  float s2 = v.x + v.y + v.z + v.w;
  float ss2 = v.x * v.x + v.y * v.y + v.z * v.z + v.w * v.w;
  block_red2(s2, ss2, tmp);
  float m2 = s2 / NE, rs2 = rsqrtf(ss2 / NE - m2 * m2 + EPSF);
  float4 b2 = *reinterpret_cast<const float4*>(lnb2 + col);
  float4 o;
  o.x = (v.x - m2) * rs2 + b2.x; o.y = (v.y - m2) * rs2 + b2.y;
  o.z = (v.z - m2) * rs2 + b2.z; o.w = (v.w - m2) * rs2 + b2.w;
  *reinterpret_cast<float4*>(hout + (size_t)b * NE + col) = o;
}

// ---------------- fused: qkv-reduce + fresh KV out + self-attn + @Wso ----------------
__global__ __launch_bounds__(256) void attn_fused(const float* __restrict__ Pqkv,
    const float* __restrict__ ast_l, const int* __restrict__ tixp,
    const float* __restrict__ Wso, float* __restrict__ spart, float* __restrict__ oast_l) {
  int b = blockIdx.x >> 4, hh = blockIdx.x & 15;
  int tid = threadIdx.x;
  int tix0 = tixp[0];
  int tixc = tix0 < 0 ? 0 : (tix0 > 255 ? 255 : tix0);
  int T = tixc + 1;
  __shared__ float qv[64];
  __shared__ float kf[64];
  __shared__ float vf[64];
  __shared__ float scb[256];
  __shared__ float red[256];
  __shared__ float pv[1024];
  __shared__ float ov[64];
  if (tid < 192) {
    int m = tid >> 6, d = tid & 63;
    const float* bp = Pqkv + (size_t)(m * 16) * 8192 + (size_t)b * 1024 + hh * 64 + d;
    float acc = 0.f;
#pragma unroll
    for (int ks = 0; ks < 16; ++ks) acc += bp[(size_t)ks * 8192];
    if (m == 2) qv[d] = acc * 0.125f;
    else {
      if (m == 0) kf[d] = acc; else vf[d] = acc;
      if (tix0 >= 0 && tix0 < NIMG) {
        int row = (m == 0) ? b : 8 + b;
        oast_l[((size_t)row * NIMG + tix0) * NE + hh * 64 + d] = acc;
      }
    }
  }
  __syncthreads();
  float sj = -INFINITY;
  if (tid < T) {
    const float* kr = (tid == tixc) ? kf : (ast_l + ((size_t)b * NIMG + tid) * NE + hh * 64);
    float s = 0.f;
#pragma unroll
    for (int d0 = 0; d0 < 64; d0 += 4) {
      float4 k4 = *reinterpret_cast<const float4*>(kr + d0);
      s += qv[d0] * k4.x + qv[d0 + 1] * k4.y + qv[d0 + 2] * k4.z + qv[d0 + 3] * k4.w;
    }
    sj = s;
  }
  red[tid] = sj; __syncthreads();
  for (int o = 128; o; o >>= 1) { if (tid < o) red[tid] = fmaxf(red[tid], red[tid + o]); __syncthreads(); }
  float mx = red[0]; __syncthreads();
  float e = (tid < T) ? __expf(sj - mx) : 0.f;
  red[tid] = e; __syncthreads();
  for (int o = 128; o; o >>= 1) { if (tid < o) red[tid] += red[tid + o]; __syncthreads(); }
  float inv = 1.f / red[0];
  scb[tid] = e * inv;
  __syncthreads();
  {
    int c = tid >> 4, d4 = (tid & 15) * 4;
    float4 a = make_float4(0.f, 0.f, 0.f, 0.f);
    for (int j = c; j < T; j += 16) {
      const float* vr = (j == tixc) ? vf : (ast_l + ((size_t)(8 + b) * NIMG + j) * NE + hh * 64);
      float4 v4 = *reinterpret_cast<const float4*>(vr + d4);
      float w = scb[j];
      a.x += w * v4.x; a.y += w * v4.y; a.z += w * v4.z; a.w += w * v4.w;
    }
    pv[c * 64 + d4 + 0] = a.x; pv[c * 64 + d4 + 1] = a.y;
    pv[c * 64 + d4 + 2] = a.z; pv[c * 64 + d4 + 3] = a.w;
  }
  __syncthreads();
  if (tid < 64) {
    float s = 0.f;
#pragma unroll
    for (int c = 0; c < 16; ++c) s += pv[c * 64 + tid];
    ov[tid] = s;
  }
  __syncthreads();
  {
    int nb = tid * 4;
    const float* wp = Wso + (size_t)(hh * 64) * NE + nb;
    float4 acc = make_float4(0.f, 0.f, 0.f, 0.f);
    for (int d = 0; d < 64; d += 8) {
      float4 w[8];
#pragma unroll
      for (int j = 0; j < 8; ++j)
        w[j] = *reinterpret_cast<const float4*>(wp + (size_t)(d + j) * NE);
#pragma unroll
      for (int j = 0; j < 8; ++j) {
        float o = ov[d + j];
        acc.x += o * w[j].x; acc.y += o * w[j].y; acc.z += o * w[j].z; acc.w += o * w[j].w;
      }
    }
    *reinterpret_cast<float4*>(spart + ((size_t)hh * 8 + b) * 1024 + nb) = acc;
  }
}

// ---------------- fused: x2/h2 LN + cross attention chain ----------------
__global__ __launch_bounds__(256) void cross_fused(const float* __restrict__ xres,
    const float* __restrict__ sspart, const float* __restrict__ sls,
    const float* __restrict__ slb, const float* __restrict__ peb,
    const float* __restrict__ Weq, const float* __restrict__ Wek,
    const float* __restrict__ Wev, const float* __restrict__ Weo,
    const float* __restrict__ X, const void* __restrict__ maskp,
    const unsigned* __restrict__ mflag, float* __restrict__ x2store,
    float* __restrict__ spart) {
  int b = blockIdx.x >> 4, hh = blockIdx.x & 15;
  int tid = threadIdx.x;
  __shared__ float vecA[NE];
  __shared__ float vecB[NE];
  __shared__ float red[256];
  __shared__ float w_[NTT];
  __shared__ float qv[64];
  __shared__ float oe[64];
  __shared__ float tmp[8];
  int mi32 = (*mflag == 1u);
  {
    int col = tid * 4;
    float4 sv = make_float4(0.f, 0.f, 0.f, 0.f);
    const float* base = sspart + (size_t)b * 1024 + col;
#pragma unroll
    for (int h = 0; h < 16; h += 8) {
      float4 w[8];
#pragma unroll
      for (int j = 0; j < 8; ++j)
        w[j] = *reinterpret_cast<const float4*>(base + (size_t)(h + j) * 8192);
#pragma unroll
      for (int j = 0; j < 8; ++j) sv = f4add(sv, w[j]);
    }
    float s = sv.x + sv.y + sv.z + sv.w;
    float ss = sv.x * sv.x + sv.y * sv.y + sv.z * sv.z + sv.w * sv.w;
    block_red2(s, ss, tmp);
    float m1 = s / NE, rs1 = rsqrtf(ss / NE - m1 * m1 + EPSF);
    float4 xv = *reinterpret_cast<const float4*>(xres + (size_t)b * NE + col);
    float4 sc1 = *reinterpret_cast<const float4*>(sls + col);
    float4 b1 = *reinterpret_cast<const float4*>(slb + col);
    float4 v;
    v.x = xv.x + (sv.x - m1) * rs1 * sc1.x + b1.x;
    v.y = xv.y + (sv.y - m1) * rs1 * sc1.y + b1.y;
    v.z = xv.z + (sv.z - m1) * rs1 * sc1.z + b1.z;
    v.w = xv.w + (sv.w - m1) * rs1 * sc1.w + b1.w;
    if (hh == 0)
      *reinterpret_cast<float4*>(x2store + (size_t)b * NE + col) = v;
    float s2 = v.x + v.y + v.z + v.w;
    float ss2 = v.x * v.x + v.y * v.y + v.z * v.z + v.w * v.w;
    block_red2(s2, ss2, tmp);
    float m2 = s2 / NE, rs2 = rsqrtf(ss2 / NE - m2 * m2 + EPSF);
    float4 b2 = *reinterpret_cast<const float4*>(peb + col);
    float4 o;
    o.x = (v.x - m2) * rs2 + b2.x; o.y = (v.y - m2) * rs2 + b2.y;
    o.z = (v.z - m2) * rs2 + b2.z; o.w = (v.w - m2) * rs2 + b2.w;
    reinterpret_cast<float4*>(vecA)[tid] = o;
  }
  __syncthreads();

  {
    int d4 = (tid & 15) * 4, ech = tid >> 4;
    const float* base = Weq + hh * 64 + d4;
    float4 a = make_float4(0.f, 0.f, 0.f, 0.f);
    for (int e = ech * 64; e < ech * 64 + 64; e += 8) {
      float4 w[8];
#pragma unroll
      for (int j = 0; j < 8; ++j)
        w[j] = *reinterpret_cast<const float4*>(base + (size_t)(e + j) * NE);
#pragma unroll
      for (int j = 0; j < 8; ++j) {
        float hv = vecA[e + j];
        a.x += hv * w[j].x; a.y += hv * w[j].y; a.z += hv * w[j].z; a.w += hv * w[j].w;
      }
    }
    vecB[ech * 64 + d4 + 0] = a.x; vecB[ech * 64 + d4 + 1] = a.y;
    vecB[ech * 64 + d4 + 2] = a.z; vecB[ech * 64 + d4 + 3] = a.w;
  }
  __syncthreads();
  if (tid < 64) {
    float s = 0.f;
#pragma unroll
    for (int c = 0; c < 16; ++c) s += vecB[c * 64 + tid];
    qv[tid] = s;
  }
  __syncthreads();

  {
    float qwtmp[4];
#pragma unroll
    for (int jj = 0; jj < 4; ++jj) {
      int e = tid + 256 * jj;
      const float* wr = Wek + (size_t)e * NE + hh * 64;
      float a = 0.f;
#pragma unroll
      for (int d0 = 0; d0 < 64; d0 += 4) {
        float4 w4 = *reinterpret_cast<const float4*>(wr + d0);
        a += qv[d0] * w4.x + qv[d0 + 1] * w4.y + qv[d0 + 2] * w4.z + qv[d0 + 3] * w4.w;
      }
      qwtmp[jj] = a;
    }
#pragma unroll
    for (int jj = 0; jj < 4; ++jj) vecB[tid + 256 * jj] = qwtmp[jj];
  }
  __syncthreads();

  {
    int t = tid & 63, ec = tid >> 6;
    const float* xr = X + ((size_t)b * NTT + t) * NE + ec * 256;
    float part = 0.f;
#pragma unroll 4
    for (int i = 0; i < 256; i += 4) {
      float4 x4 = *reinterpret_cast<const float4*>(xr + i);
      part += vecB[ec * 256 + i] * x4.x + vecB[ec * 256 + i + 1] * x4.y +
              vecB[ec * 256 + i + 2] * x4.z + vecB[ec * 256 + i + 3] * x4.w;
    }
    red[ec * 64 + t] = part;
  }
  __syncthreads();
  float sco = -INFINITY;
  if (tid < 64) {
    float s = (red[tid] + red[64 + tid] + red[128 + tid] + red[192 + tid]) * 0.125f;
    int idx = b * NTT + tid;
    bool valid = mi32 ? (((const int*)maskp)[idx] != 0)
                      : (((const unsigned char*)maskp)[idx] != 0);
    sco = valid ? s : -INFINITY;
  }
  __syncthreads();
  red[tid] = (tid < 64) ? sco : -INFINITY; __syncthreads();
  for (int o = 128; o; o >>= 1) { if (tid < o) red[tid] = fmaxf(red[tid], red[tid + o]); __syncthreads(); }
  float mx = red[0]; __syncthreads();
  float e = (tid < 64) ? __expf(sco - mx) : 0.f;
  red[tid] = e; __syncthreads();
  for (int o = 128; o; o >>= 1) { if (tid < o) red[tid] += red[tid + o]; __syncthreads(); }
  if (tid < 64) w_[tid] = e / red[0];
  __syncthreads();

  {
    float4 a = make_float4(0.f, 0.f, 0.f, 0.f);
    const float* xb = X + (size_t)b * NTT * NE + tid * 4;
    for (int t = 0; t < NTT; t += 4) {
#pragma unroll
      for (int j = 0; j < 4; ++j) {
        float4 x4 = *reinterpret_cast<const float4*>(xb + (size_t)(t + j) * NE);
        float w = w_[t + j];
        a.x += w * x4.x; a.y += w * x4.y; a.z += w * x4.z; a.w += w * x4.w;
      }
    }
    reinterpret_cast<float4*>(vecA)[tid] = a;
  }
  __syncthreads();

  {
    int d4 = (tid & 15) * 4, ech = tid >> 4;
    const float* base = Wev + hh * 64 + d4;
    float4 a = make_float4(0.f, 0.f, 0.f, 0.f);
    for (int e = ech * 64; e < ech * 64 + 64; e += 8) {
      float4 w[8];
#pragma unroll
      for (int j = 0; j < 8; ++j)
        w[j] = *reinterpret_cast<const float4*>(base + (size_t)(e + j) * NE);
#pragma unroll
      for (int j = 0; j < 8; ++j) {
        float hv = vecA[e + j];
        a.x += hv * w[j].x; a.y += hv * w[j].y; a.z += hv * w[j].z; a.w += hv * w[j].w;
      }
    }
    vecB[ech * 64 + d4 + 0] = a.x; vecB[ech * 64 + d4 + 1] = a.y;
    vecB[ech * 64 + d4 + 2] = a.z; vecB[ech * 64 + d4 + 3] = a.w;
  }
  __syncthreads();
  if (tid < 64) {
    float s = 0.f;
#pragma unroll
    for (int c = 0; c < 16; ++c) s += vecB[c * 64 + tid];
    oe[tid] = s;
  }
  __syncthreads();

  {
    int nb = tid * 4;
    const float* wp = Weo + (size_t)(hh * 64) * NE + nb;
    float4 acc = make_float4(0.f, 0.f, 0.f, 0.f);
    for (int d = 0; d < 64; d += 8) {
      float4 w[8];
#pragma unroll
      for (int j = 0; j < 8; ++j)
        w[j] = *reinterpret_cast<const float4*>(wp + (size_t)(d + j) * NE);
#pragma unroll
      for (int j = 0; j < 8; ++j) {
        float o = oe[d + j];
        acc.x += o * w[j].x; acc.y += o * w[j].y; acc.z += o * w[j].z; acc.w += o * w[j].w;
      }
    }
    *reinterpret_cast<float4*>(spart + ((size_t)hh * 8 + b) * 1024 + nb) = acc;
  }
}

// ---------------- reduce lm_head partials -> logits ----------------
__global__ __launch_bounds__(256) void reduce_logits(const float* __restrict__ P,
                                                     float* __restrict__ logits) {
  int r = blockIdx.x / 17, cc = blockIdx.x % 17;
  int col = cc * 1024 + threadIdx.x * 4;
  if (col >= NV) return;
  if (col + 3 < NV) {
    const float* base = P + (size_t)r * NVPAD + col;
    float4 acc = make_float4(0.f, 0.f, 0.f, 0.f);
    for (int ks = 0; ks < 16; ks += 8) {
      float4 w[8];
#pragma unroll
      for (int j = 0; j < 8; ++j)
        w[j] = *reinterpret_cast<const float4*>(base + (size_t)(ks + j) * 8 * NVPAD);
#pragma unroll
      for (int j = 0; j < 8; ++j) acc = f4add(acc, w[j]);
    }
    *reinterpret_cast<float4*>(logits + (size_t)r * NV + col) = acc;
  } else {
    for (int c = 0; c < 4 && col + c < NV; ++c) {
      float a = 0.f;
      for (int ks = 0; ks < 16; ++ks) a += P[((size_t)ks * 8 + r) * NVPAD + col + c];
      logits[(size_t)r * NV + col + c] = a;
    }
  }
}

extern "C" void kernel_launch(void* const* d_in, const int* in_sizes, int n_in,
                              void* d_out, int out_size, void* d_ws, size_t ws_size,
                              hipStream_t stream) {
  const float* enc_state = (const float*)d_in[0];
  const float* ast_in    = (const float*)d_in[1];
  const void* amask      = d_in[2];
  const int* prev = (const int*)d_in[3];
  const int* tix  = (const int*)d_in[4];
  const float* embed_tok = (const float*)d_in[5];
  const float* embed_pos = (const float*)d_in[6];
  const float* lnemb_s = (const float*)d_in[7];
  const float* lnemb_b = (const float*)d_in[8];
  const float* psb = (const float*)d_in[9];
  const float* Wsq = (const float*)d_in[10];
  const float* Wsk = (const float*)d_in[11];
  const float* Wsv = (const float*)d_in[12];
  const float* Wso = (const float*)d_in[13];
  const float* sls = (const float*)d_in[14];
  const float* slb = (const float*)d_in[15];
  const float* peb = (const float*)d_in[16];
  const float* Weq = (const float*)d_in[17];
  const float* Wek = (const float*)d_in[18];
  const float* Wev = (const float*)d_in[19];
  const float* Weo = (const float*)d_in[20];
  const float* els = (const float*)d_in[21];
  const float* elb = (const float*)d_in[22];
  const float* g0b = (const float*)d_in[23];
  const float* Wf0 = (const float*)d_in[24];
  const float* Wf1 = (const float*)d_in[25];
  const float* g1b = (const float*)d_in[26];
  const float* Wf2 = (const float*)d_in[27];
  const float* flb = (const float*)d_in[28];
  const float* Wlm = (const float*)d_in[29];

  float* ws = (float*)d_ws;
  float* logits = (float*)d_out;
  float* out_ast = logits + (size_t)NB * NV;

  embed_copy<<<4104, 256, 0, stream>>>(embed_tok, embed_pos, prev, tix, lnemb_b, lnemb_s,
                                       amask, ws + XBUF, ws + XSTAT,
                                       (unsigned*)(ws + MFLAG),
                                       (const float4*)ast_in, (float4*)out_ast);

  for (int l = 0; l < NL; ++l) {
    size_t wE = (size_t)l * NE * NE;
    size_t wG = (size_t)l * NE * NG;

    {  // qkv partials: C=1, CB=4, KS=16, LN-from-stats prologue
      MvP p{}; p.W0 = Wsk + wE; p.W1 = Wsv + wE; p.W2 = Wsq + wE;
      p.pout = ws + P_QKV; p.xsrc = ws + XBUF; p.stats = ws + XSTAT;
      p.bias = psb + (size_t)l * NE;
      p.K = NE; p.N = NE; p.NPAD = NE; p.CB = 4; p.KS = 16; p.mode = 1; p.nchunk = 4;
      mv_k<1><<<3 * 4 * 16, 256, 0, stream>>>(p);
    }
    attn_fused<<<NB * NH, 256, 0, stream>>>(ws + P_QKV,
                                            ast_in + (size_t)l * 16 * NIMG * NE, tix,
                                            Wso + wE, ws + SSPART,
                                            out_ast + (size_t)l * 16 * NIMG * NE);
    cross_fused<<<NB * NH, 256, 0, stream>>>(ws + XBUF, ws + SSPART,
                                             sls + (size_t)l * NE, slb + (size_t)l * NE,
                                             peb + (size_t)l * NE,
                                             Weq + wE, Wek + wE, Wev + wE, Weo + wE,
                                             enc_state, amask,
                                             (const unsigned*)(ws + MFLAG),
                                             ws + DX2, ws + SEPART);
    ln_res_sum<<<NB, 256, 0, stream>>>(ws + DX2, ws + SEPART, els + (size_t)l * NE,
                                       elb + (size_t)l * NE, g0b + (size_t)l * NE,
                                       ws + DX3, ws + DH3);
    {  // fc0/fc1 partials: C=1, CB=16, KS=8, precomputed h3
      MvP p{}; p.W0 = Wf0 + wG; p.W1 = Wf1 + wG;
      p.pout = ws + P_FC01; p.hsrc = ws + DH3;
      p.K = NE; p.N = NG; p.NPAD = NG; p.CB = 16; p.KS = 8; p.mode = 0;
      mv_k<1><<<2 * 16 * 8, 256, 0, stream>>>(p);
    }
    combine_g<<<64, 256, 0, stream>>>(ws + P_FC01, ws + DG, ws + GSTAT);
    {  // fc2 partials: C=1, CB=4, KS=32, LN(g)-from-stats prologue
      MvP p{}; p.W0 = Wf2 + (size_t)l * NG * NE;
      p.pout = ws + P_FC2; p.xsrc = ws + DG; p.stats = ws + GSTAT;
      p.bias = g1b + (size_t)l * NG;
      p.K = NG; p.N = NE; p.NPAD = NE; p.CB = 4; p.KS = 32; p.mode = 1; p.nchunk = 8;
      mv_k<1><<<4 * 32, 256, 0, stream>>>(p);
    }
    combine_x<<<32, 256, 0, stream>>>(ws + P_FC2, ws + DX3, ws + XBUF, ws + XSTAT);
  }
  {  // lm_head partials: C=4, CB=17, KS=16, LN(x4)-from-stats prologue
    MvP p{}; p.W0 = Wlm;
    p.pout = ws + P_LM; p.xsrc = ws + XBUF; p.stats = ws + XSTAT; p.bias = flb;
    p.K = NE; p.N = NV; p.NPAD = NVPAD; p.CB = 17; p.KS = 16; p.mode = 1; p.nchunk = 4;
    mv_k<4><<<17 * 16, 256, 0, stream>>>(p);
  }
  reduce_logits<<<NB * 17, 256, 0, stream>>>(ws + P_LM, logits);
}